// Round 12
// baseline (924.408 us; speedup 1.0000x reference)
//
#include <hip/hip_runtime.h>
#include <hip/hip_bf16.h>

typedef __bf16 bf16;
typedef __bf16 bf16x8 __attribute__((ext_vector_type(8)));
typedef float f32x4 __attribute__((ext_vector_type(4)));
typedef unsigned int u32;

#define D_    2048
#define NSEQ  4096
#define BATCH 2
#define CH    1024   // recurrence chunk (math is chunk-size invariant)
#define TC    4      // chunks per batch
#define MROWS 8192   // BATCH*NSEQ

__device__ __forceinline__ void gload16(const bf16* g, bf16* l) {
  __builtin_amdgcn_global_load_lds(
      (const __attribute__((address_space(1))) u32*)g,
      (__attribute__((address_space(3))) u32*)l, 16, 0, 0);
}

// ============ 128^2 core, minimal 2-phase (recurrence kernels; proven) ======

struct SmemTiles {
  alignas(16) bf16 As[2][128 * 32];
  alignas(16) bf16 Bs[2][128 * 32];
};

__device__ __forceinline__ void stage128(SmemTiles& sm, int bb, const bf16* A,
                                         int lda, const bf16* B, int ldb,
                                         int k0, int tid) {
#pragma unroll
  for (int it = 0; it < 2; ++it) {
    int c = it * 256 + tid;      // 16B chunk index, 512 chunks per tile
    int r = c >> 2;              // 4 chunks per 32-elem row
    int co = (c & 3) << 3;
    gload16(A + (size_t)r * lda + k0 + co, &sm.As[bb][c * 8]);
    gload16(B + (size_t)r * ldb + k0 + co, &sm.Bs[bb][c * 8]);
  }
}

__device__ __forceinline__ void gemm_core(SmemTiles& sm, const bf16* A, int lda,
                                          const bf16* B, int ldb, int K,
                                          f32x4 acc[4][4]) {
  const int tid = threadIdx.x;
  const int lane = tid & 63;
  const int wave = tid >> 6;
  const int wr = wave >> 1, wc = wave & 1;
  const int l15 = lane & 15, kl = lane >> 4;
  const int NT = K >> 5;
  if (NT <= 0) return;

  stage128(sm, 0, A, lda, B, ldb, 0, tid);
  __syncthreads();

  const int ao = (wr * 64 + l15) * 32 + kl * 8;
  const int bo = (wc * 64 + l15) * 32 + kl * 8;

  for (int t = 0; t < NT; ++t) {
    if (t + 1 < NT)
      stage128(sm, (t + 1) & 1, A, lda, B, ldb, (t + 1) * 32, tid);
    const bf16* Ab = sm.As[t & 1];
    const bf16* Bb = sm.Bs[t & 1];
    bf16x8 a[4], b[4];
#pragma unroll
    for (int m = 0; m < 4; ++m) a[m] = *(const bf16x8*)(Ab + ao + m * 16 * 32);
#pragma unroll
    for (int n = 0; n < 4; ++n) b[n] = *(const bf16x8*)(Bb + bo + n * 16 * 32);
    __builtin_amdgcn_s_setprio(1);
#pragma unroll
    for (int m = 0; m < 4; ++m)
#pragma unroll
      for (int n = 0; n < 4; ++n)
        acc[m][n] = __builtin_amdgcn_mfma_f32_16x16x32_bf16(a[m], b[n], acc[m][n], 0, 0, 0);
    __builtin_amdgcn_s_setprio(0);
    if (t + 1 < NT) __syncthreads();
  }
}

#define EPILOGUE_VARS                              \
  const int lane = threadIdx.x & 63;               \
  const int wave = threadIdx.x >> 6;               \
  const int wr = wave >> 1, wc = wave & 1;         \
  const int l15 = lane & 15, kl = lane >> 4;

// ============ 128x256 big-GEMM core: counted-vmcnt 2-deep (R11, proven) =====

struct SmemW {
  alignas(16) bf16 A[2][128 * 32];   // 8 slabs x 512 elems per buffer
  alignas(16) bf16 B[2][256 * 32];   // 16 slabs per buffer
};

__device__ __forceinline__ void stageW(SmemW& sm, int bb, const bf16* A,
                                       int lda, const bf16* B, int ldb,
                                       int k0, int wave, int lane) {
  const int r16 = lane & 15, c8 = lane >> 4;
  gload16(A + (size_t)(wave * 16 + r16) * lda + k0 + c8 * 8,
          &sm.A[bb][wave * 512 + lane * 8]);
#pragma unroll
  for (int j = 0; j < 2; ++j) {
    int nb = 2 * wave + j;
    gload16(B + (size_t)(nb * 16 + r16) * ldb + k0 + c8 * 8,
            &sm.B[bb][nb * 512 + lane * 8]);
  }
}

__device__ __forceinline__ void gemmW_core(SmemW& sm, const bf16* A, int lda,
                                           const bf16* B, int ldb, int K,
                                           f32x4 acc[4][4]) {
  const int tid = threadIdx.x;
  const int wave = tid >> 6, lane = tid & 63;
  const int wr = wave >> 2, wc = wave & 3;
  const int NT = K >> 5;
  if (NT <= 0) return;

  stageW(sm, 0, A, lda, B, ldb, 0, wave, lane);
  if (NT > 1) {
    stageW(sm, 1, A, lda, B, ldb, 32, wave, lane);
    asm volatile("s_waitcnt vmcnt(3)" ::: "memory");  // tile 0 resident (own)
  } else {
    asm volatile("s_waitcnt vmcnt(0)" ::: "memory");
  }
  __builtin_amdgcn_s_barrier();  // tile 0 resident for ALL waves

  const int aoff = wr * 2048 + lane * 8;  // slabs wr*4..+3
  const int boff = wc * 2048 + lane * 8;  // slabs wc*4..+3

  for (int t = 0; t < NT; ++t) {
    const bf16* Ab = sm.A[t & 1];
    const bf16* Bb = sm.B[t & 1];
    bf16x8 av[4], bv[4];
#pragma unroll
    for (int m = 0; m < 4; ++m) av[m] = *(const bf16x8*)&Ab[aoff + m * 512];
#pragma unroll
    for (int n = 0; n < 4; ++n) bv[n] = *(const bf16x8*)&Bb[boff + n * 512];
    asm volatile("s_waitcnt lgkmcnt(0)" ::: "memory");  // my reads done
    __builtin_amdgcn_s_barrier();                       // all waves' reads done
    if (t + 2 < NT)                                     // refill freed buffer
      stageW(sm, t & 1, A, lda, B, ldb, (t + 2) * 32, wave, lane);
    __builtin_amdgcn_s_setprio(1);
#pragma unroll
    for (int m = 0; m < 4; ++m)
#pragma unroll
      for (int n = 0; n < 4; ++n)
        acc[m][n] = __builtin_amdgcn_mfma_f32_16x16x32_bf16(av[m], bv[n],
                                                            acc[m][n], 0, 0, 0);
    __builtin_amdgcn_s_setprio(0);
    if (t + 1 < NT) {
      if (t + 2 < NT)
        asm volatile("s_waitcnt vmcnt(3)" ::: "memory");  // t+1 resident
      else
        asm volatile("s_waitcnt vmcnt(0)" ::: "memory");
      __builtin_amdgcn_s_barrier();
    }
  }
}

#define EPILOGUEW_VARS                             \
  const int lane = threadIdx.x & 63;               \
  const int wave = threadIdx.x >> 6;               \
  const int wr = wave >> 2, wc = wave & 3;         \
  const int l15 = lane & 15, kl = lane >> 4;

// ---------------- elementwise kernels ----------------

__global__ __launch_bounds__(256) void k_f2b(const float* __restrict__ in,
                                             bf16* __restrict__ out) {
  int i = (blockIdx.x * 256 + threadIdx.x) * 8;
  float4 a = *(const float4*)(in + i);
  float4 b = *(const float4*)(in + i + 4);
  bf16x8 o;
  o[0] = (bf16)a.x; o[1] = (bf16)a.y; o[2] = (bf16)a.z; o[3] = (bf16)a.w;
  o[4] = (bf16)b.x; o[5] = (bf16)b.y; o[6] = (bf16)b.z; o[7] = (bf16)b.w;
  *(bf16x8*)(out + i) = o;
}

// convert two 2048x2048 fp32 weights into one contiguous bf16 buffer
__global__ __launch_bounds__(256) void k_f2b2(const float* __restrict__ in0,
                                              const float* __restrict__ in1,
                                              bf16* __restrict__ out) {
  int i = (blockIdx.x * 256 + threadIdx.x) * 8;
  const float* src = (i < D_ * D_) ? in0 : in1;
  int off = (i < D_ * D_) ? i : i - D_ * D_;
  float4 a = *(const float4*)(src + off);
  float4 b = *(const float4*)(src + off + 4);
  bf16x8 o;
  o[0] = (bf16)a.x; o[1] = (bf16)a.y; o[2] = (bf16)a.z; o[3] = (bf16)a.w;
  o[4] = (bf16)b.x; o[5] = (bf16)b.y; o[6] = (bf16)b.z; o[7] = (bf16)b.w;
  *(bf16x8*)(out + i) = o;
}

__global__ __launch_bounds__(256) void k_rms(const float* __restrict__ x,
                                             bf16* __restrict__ xn) {
  const int row = blockIdx.x;
  const int tid = threadIdx.x;
  const float* xr = x + (size_t)row * D_;
  float4 a = *(const float4*)(xr + tid * 8);
  float4 b = *(const float4*)(xr + tid * 8 + 4);
  float ss = a.x * a.x + a.y * a.y + a.z * a.z + a.w * a.w +
             b.x * b.x + b.y * b.y + b.z * b.z + b.w * b.w;
#pragma unroll
  for (int o = 32; o > 0; o >>= 1) ss += __shfl_xor(ss, o, 64);
  __shared__ float red[4];
  if ((tid & 63) == 0) red[tid >> 6] = ss;
  __syncthreads();
  float tot = red[0] + red[1] + red[2] + red[3];
  float sc = rsqrtf(tot * (1.f / D_) + 1.1920928955078125e-07f);
  bf16x8 o;
  o[0] = (bf16)(a.x * sc); o[1] = (bf16)(a.y * sc);
  o[2] = (bf16)(a.z * sc); o[3] = (bf16)(a.w * sc);
  o[4] = (bf16)(b.x * sc); o[5] = (bf16)(b.y * sc);
  o[6] = (bf16)(b.z * sc); o[7] = (bf16)(b.w * sc);
  *(bf16x8*)(xn + (size_t)row * D_ + tid * 8) = o;
}

// ---------------- fused pairwise projection GEMM ----------------
// C = act(xn @ [W0;W1]^T): one launch covers TWO projections (N=4096).
// Grid (4096/256=16, 8192/128=64) = 1024 blocks -> 3 blocks/CU (LDS-bound).
// Block's 256-col span lies entirely in one projection (2048 % 256 == 0);
// epilogue branches block-uniformly on pid = col0 >> 11.
// SMODE bit0: store normal [8192,2048]; bit1: store transposed [B][D][N].

template <int ACT0, int SM0, int ACT1, int SM1>
__global__ __launch_bounds__(512, 4) void k_projF(const bf16* __restrict__ xn,
                                                  const bf16* __restrict__ Wcat,
                                                  bf16* __restrict__ Cn0,
                                                  bf16* __restrict__ Ct0,
                                                  bf16* __restrict__ Cn1,
                                                  bf16* __restrict__ Ct1) {
  __shared__ SmemW sm;
  const int row0 = blockIdx.y * 128, col0 = blockIdx.x * 256;
  f32x4 acc[4][4] = {};
  gemmW_core(sm, xn + (size_t)row0 * D_, D_, Wcat + (size_t)col0 * D_, D_, D_, acc);
  EPILOGUEW_VARS
  const int pid = col0 >> 11;          // 0: first projection, 1: second
  const int cb = (col0 & 2047) + wc * 64;
#pragma unroll
  for (int m = 0; m < 4; ++m)
#pragma unroll
    for (int n = 0; n < 4; ++n)
#pragma unroll
      for (int j = 0; j < 4; ++j) {
        int r = row0 + wr * 64 + m * 16 + kl * 4 + j;
        int c = cb + n * 16 + l15;
        float v = acc[m][n][j];
        if (pid == 0) {
          if (ACT0 == 1) v = v / (1.f + __expf(-v));
          if (ACT0 == 2) v = 1.f / (1.f + __expf(-v));
          bf16 ob = (bf16)v;
          if (SM0 & 1) Cn0[(size_t)r * D_ + c] = ob;
          if (SM0 & 2)
            Ct0[((size_t)(r >> 12) * D_ + c) * NSEQ + (r & (NSEQ - 1))] = ob;
        } else {
          if (ACT1 == 1) v = v / (1.f + __expf(-v));
          if (ACT1 == 2) v = 1.f / (1.f + __expf(-v));
          bf16 ob = (bf16)v;
          if (SM1 & 1) Cn1[(size_t)r * D_ + c] = ob;
          if (SM1 & 2)
            Ct1[((size_t)(r >> 12) * D_ + c) * NSEQ + (r & (NSEQ - 1))] = ob;
        }
      }
}

// out = og @ Wp^T (fp32 store)
__global__ __launch_bounds__(512, 4) void k_final2(const bf16* __restrict__ og,
                                                   const bf16* __restrict__ Wp,
                                                   float* __restrict__ out) {
  __shared__ SmemW sm;
  const int row0 = blockIdx.y * 128, col0 = blockIdx.x * 256;
  f32x4 acc[4][4] = {};
  gemmW_core(sm, og + (size_t)row0 * D_, D_, Wp + (size_t)col0 * D_, D_, D_, acc);
  EPILOGUEW_VARS
#pragma unroll
  for (int m = 0; m < 4; ++m)
#pragma unroll
    for (int n = 0; n < 4; ++n)
#pragma unroll
      for (int j = 0; j < 4; ++j) {
        int r = row0 + wr * 64 + m * 16 + kl * 4 + j;
        int c = col0 + wc * 64 + n * 16 + l15;
        out[(size_t)r * D_ + c] = acc[m][n][j];
      }
}

// ---------------- chunked-recurrence kernels (128^2 core) ----------------

// s[z] = tril(q_t k_t^T), z = b*TC + t, chunk CH=1024.
__global__ __launch_bounds__(256) void k_scores(const bf16* __restrict__ q,
                                                const bf16* __restrict__ k,
                                                bf16* __restrict__ s) {
  const int z = blockIdx.z, b = z >> 2, t = z & 3;
  const int row0 = blockIdx.y * 128, col0 = blockIdx.x * 128;
  if (col0 > row0) return;  // strictly upper tile
  __shared__ SmemTiles sm;
  f32x4 acc[4][4] = {};
  gemm_core(sm, q + (size_t)(b * NSEQ + t * CH + row0) * D_, D_,
                k + (size_t)(b * NSEQ + t * CH + col0) * D_, D_, D_, acc);
  EPILOGUE_VARS
  bf16* sp = s + (size_t)z * CH * CH;
#pragma unroll
  for (int m = 0; m < 4; ++m)
#pragma unroll
    for (int n = 0; n < 4; ++n)
#pragma unroll
      for (int j = 0; j < 4; ++j) {
        int i = row0 + wr * 64 + m * 16 + kl * 4 + j;
        int jc = col0 + wc * 64 + n * 16 + l15;
        float v = (i >= jc) ? acc[m][n][j] : 0.f;
        sp[(size_t)i * CH + jc] = (bf16)v;
      }
}

// og[chunk rows] = s @ v  (intra-chunk; K trimmed to lower-tri extent)
__global__ __launch_bounds__(256) void k_ointra(const bf16* __restrict__ s,
                                                const bf16* __restrict__ vT,
                                                bf16* __restrict__ og) {
  __shared__ SmemTiles sm;
  const int z = blockIdx.z, b = z >> 2, t = z & 3;
  const int row0 = blockIdx.y * 128, col0 = blockIdx.x * 128;
  const int K = row0 + 128;
  f32x4 acc[4][4] = {};
  gemm_core(sm, s + (size_t)z * CH * CH + (size_t)row0 * CH, CH,
                vT + (size_t)b * D_ * NSEQ + (size_t)col0 * NSEQ + t * CH, NSEQ,
                K, acc);
  EPILOGUE_VARS
#pragma unroll
  for (int m = 0; m < 4; ++m)
#pragma unroll
    for (int n = 0; n < 4; ++n)
#pragma unroll
      for (int j = 0; j < 4; ++j) {
        int i = row0 + wr * 64 + m * 16 + kl * 4 + j;
        int c = col0 + wc * 64 + n * 16 + l15;
        og[(size_t)(b * NSEQ + t * CH + i) * D_ + c] = (bf16)acc[m][n][j];
      }
}

// og = (og + q_t @ kvT^T) * g   (Kin==0 for t==0: just gate)
__global__ __launch_bounds__(256) void k_ointer(const bf16* __restrict__ q,
                                                const bf16* __restrict__ kvb,
                                                const bf16* __restrict__ g,
                                                bf16* __restrict__ og, int t,
                                                int Kin) {
  __shared__ SmemTiles sm;
  const int b = blockIdx.z;
  const int row0 = blockIdx.y * 128, col0 = blockIdx.x * 128;
  f32x4 acc[4][4] = {};
  gemm_core(sm, q + (size_t)(b * NSEQ + t * CH + row0) * D_, D_,
                kvb + (size_t)b * D_ * D_ + (size_t)col0 * D_, D_, Kin, acc);
  EPILOGUE_VARS
#pragma unroll
  for (int m = 0; m < 4; ++m)
#pragma unroll
    for (int n = 0; n < 4; ++n)
#pragma unroll
      for (int j = 0; j < 4; ++j) {
        int i = row0 + wr * 64 + m * 16 + kl * 4 + j;
        int c = col0 + wc * 64 + n * 16 + l15;
        size_t idx = (size_t)(b * NSEQ + t * CH + i) * D_ + c;
        float v = ((float)og[idx] + acc[m][n][j]) * (float)g[idx];
        og[idx] = (bf16)v;
      }
}

// kvT[b][e][d] += sum_{j in chunk t} v[j][e] k[j][d]  (bf16 accumulation;
// t==0 writes without reading so no memset/poison hazard)
__global__ __launch_bounds__(256) void k_update(const bf16* __restrict__ vT,
                                                const bf16* __restrict__ kT,
                                                bf16* __restrict__ kvb, int t) {
  __shared__ SmemTiles sm;
  const int b = blockIdx.z;
  const int row0 = blockIdx.y * 128, col0 = blockIdx.x * 128;
  f32x4 acc[4][4] = {};
  gemm_core(sm, vT + (size_t)b * D_ * NSEQ + (size_t)row0 * NSEQ + t * CH, NSEQ,
                kT + (size_t)b * D_ * NSEQ + (size_t)col0 * NSEQ + t * CH, NSEQ,
                CH, acc);
  EPILOGUE_VARS
#pragma unroll
  for (int m = 0; m < 4; ++m)
#pragma unroll
    for (int n = 0; n < 4; ++n)
#pragma unroll
      for (int j = 0; j < 4; ++j) {
        int e = row0 + wr * 64 + m * 16 + kl * 4 + j;
        int d = col0 + wc * 64 + n * 16 + l15;
        size_t idx = (size_t)b * D_ * D_ + (size_t)e * D_ + d;
        float v = acc[m][n][j];
        if (t > 0) v += (float)kvb[idx];
        kvb[idx] = (bf16)v;
      }
}

// ---------------- host launch ----------------
//
// Workspace plan (~145 MiB, same as proven R11): xn/og 32 | kT 32 | vT 32 |
// k 32 | shared 16.78 {Wpair -> s -> kvb -> Wpb}.
// q,g live in d_out (both dead before k_final2 overwrites it).
// Projections fused pairwise: [Wq;Wk] then [Wv;Wg], each one N=4096 GEMM
// (1024 blocks, 3/CU) with per-half activation/store epilogue.

extern "C" void kernel_launch(void* const* d_in, const int* in_sizes, int n_in,
                              void* d_out, int out_size, void* d_ws, size_t ws_size,
                              hipStream_t stream) {
  (void)in_sizes; (void)n_in; (void)out_size; (void)ws_size;
  const float* x  = (const float*)d_in[0];
  const float* Wq = (const float*)d_in[1];
  const float* Wk = (const float*)d_in[2];
  const float* Wv = (const float*)d_in[3];
  const float* Wg = (const float*)d_in[4];
  const float* Wp = (const float*)d_in[5];
  float* out = (float*)d_out;

  char* p = (char*)d_ws;
  auto take = [&](size_t bytes) {
    char* r = p;
    p += (bytes + 255) & ~(size_t)255;
    return r;
  };
  const size_t MD2 = (size_t)MROWS * D_ * 2;

  bf16* xn  = (bf16*)take(MD2);                        // reused as og
  bf16* kT  = (bf16*)take(MD2);
  bf16* vT  = (bf16*)take(MD2);
  bf16* k   = (bf16*)take((size_t)MROWS * D_ * 2);     // scores operand
  char* shared = take((size_t)BATCH * TC * CH * CH * 2);  // 16.78 MiB region
  bf16* Wpair = (bf16*)shared;    // [2*2048, 2048] bf16, then s, then kvb, then Wp
  bf16* s    = (bf16*)shared;
  bf16* kvb  = (bf16*)shared;
  bf16* og = xn;

  bf16* q = (bf16*)d_out;
  bf16* g = (bf16*)d_out + (size_t)MROWS * D_;

  dim3 gpF(2 * D_ / 256, MROWS / 128);  // (16, 64) = 1024 blocks, 3/CU
  dim3 gpW(D_ / 256, MROWS / 128);      // (8, 64)  = 512 blocks

  k_rms<<<MROWS, 256, 0, stream>>>(x, xn);

  // q = silu(xn Wq^T) -> normal; k = silu(xn Wk^T) -> normal + transposed
  k_f2b2<<<2 * (D_ * D_) / 2048, 256, 0, stream>>>(Wq, Wk, Wpair);
  k_projF<1, 1, 1, 3><<<gpF, 512, 0, stream>>>(xn, Wpair, q, (bf16*)nullptr,
                                               k, kT);
  // v = silu(xn Wv^T) -> transposed only; g = sigmoid(xn Wg^T) -> normal
  k_f2b2<<<2 * (D_ * D_) / 2048, 256, 0, stream>>>(Wv, Wg, Wpair);
  k_projF<1, 2, 2, 1><<<gpF, 512, 0, stream>>>(xn, Wpair, (bf16*)nullptr, vT,
                                               g, (bf16*)nullptr);

  // intra-chunk: masked scores (lower-tri tiles only) then s @ v
  k_scores<<<dim3(CH / 128, CH / 128, BATCH * TC), 256, 0, stream>>>(q, k, s);
  k_ointra<<<dim3(D_ / 128, CH / 128, BATCH * TC), 256, 0, stream>>>(s, vT, og);

  // s dead; region becomes the bf16 KV state (written by update t=0)
  for (int t = 0; t < TC; ++t) {
    k_ointer<<<dim3(D_ / 128, CH / 128, BATCH), 256, 0, stream>>>(
        q, kvb, g, og, t, t ? D_ : 0);
    if (t < TC - 1)
      k_update<<<dim3(D_ / 128, D_ / 128, BATCH), 256, 0, stream>>>(vT, kT,
                                                                    kvb, t);
  }

  // kvb dead; region hosts the bf16 Wp
  bf16* Wpb = (bf16*)shared;
  k_f2b<<<(D_ * D_) / 2048, 256, 0, stream>>>(Wp, Wpb);
  k_final2<<<gpW, 512, 0, stream>>>(og, Wpb, out);
}

// Round 13
// 880.636 us; speedup vs baseline: 1.0497x; 1.0497x over previous
//
#include <hip/hip_runtime.h>
#include <hip/hip_bf16.h>

typedef __bf16 bf16;
typedef __bf16 bf16x8 __attribute__((ext_vector_type(8)));
typedef float f32x4 __attribute__((ext_vector_type(4)));
typedef unsigned int u32;

#define D_    2048
#define NSEQ  4096
#define BATCH 2
#define CH    1024   // recurrence chunk (math is chunk-size invariant)
#define TC    4      // chunks per batch
#define MROWS 8192   // BATCH*NSEQ

__device__ __forceinline__ void gload16(const bf16* g, bf16* l) {
  __builtin_amdgcn_global_load_lds(
      (const __attribute__((address_space(1))) u32*)g,
      (__attribute__((address_space(3))) u32*)l, 16, 0, 0);
}

// ============ 128^2 core, minimal 2-phase (recurrence kernels; proven) ======

struct SmemTiles {
  alignas(16) bf16 As[2][128 * 32];
  alignas(16) bf16 Bs[2][128 * 32];
};

__device__ __forceinline__ void stage128(SmemTiles& sm, int bb, const bf16* A,
                                         int lda, const bf16* B, int ldb,
                                         int k0, int tid) {
#pragma unroll
  for (int it = 0; it < 2; ++it) {
    int c = it * 256 + tid;      // 16B chunk index, 512 chunks per tile
    int r = c >> 2;              // 4 chunks per 32-elem row
    int co = (c & 3) << 3;
    gload16(A + (size_t)r * lda + k0 + co, &sm.As[bb][c * 8]);
    gload16(B + (size_t)r * ldb + k0 + co, &sm.Bs[bb][c * 8]);
  }
}

__device__ __forceinline__ void gemm_core(SmemTiles& sm, const bf16* A, int lda,
                                          const bf16* B, int ldb, int K,
                                          f32x4 acc[4][4]) {
  const int tid = threadIdx.x;
  const int lane = tid & 63;
  const int wave = tid >> 6;
  const int wr = wave >> 1, wc = wave & 1;
  const int l15 = lane & 15, kl = lane >> 4;
  const int NT = K >> 5;
  if (NT <= 0) return;

  stage128(sm, 0, A, lda, B, ldb, 0, tid);
  __syncthreads();

  const int ao = (wr * 64 + l15) * 32 + kl * 8;
  const int bo = (wc * 64 + l15) * 32 + kl * 8;

  for (int t = 0; t < NT; ++t) {
    if (t + 1 < NT)
      stage128(sm, (t + 1) & 1, A, lda, B, ldb, (t + 1) * 32, tid);
    const bf16* Ab = sm.As[t & 1];
    const bf16* Bb = sm.Bs[t & 1];
    bf16x8 a[4], b[4];
#pragma unroll
    for (int m = 0; m < 4; ++m) a[m] = *(const bf16x8*)(Ab + ao + m * 16 * 32);
#pragma unroll
    for (int n = 0; n < 4; ++n) b[n] = *(const bf16x8*)(Bb + bo + n * 16 * 32);
    __builtin_amdgcn_s_setprio(1);
#pragma unroll
    for (int m = 0; m < 4; ++m)
#pragma unroll
      for (int n = 0; n < 4; ++n)
        acc[m][n] = __builtin_amdgcn_mfma_f32_16x16x32_bf16(a[m], b[n], acc[m][n], 0, 0, 0);
    __builtin_amdgcn_s_setprio(0);
    if (t + 1 < NT) __syncthreads();
  }
}

#define EPILOGUE_VARS                              \
  const int lane = threadIdx.x & 63;               \
  const int wave = threadIdx.x >> 6;               \
  const int wr = wave >> 1, wc = wave & 1;         \
  const int l15 = lane & 15, kl = lane >> 4;

// ============ 256^2 big-GEMM core: 3-buffer ring, fine 2-phase/K-tile =======
//
// m201-pattern phases with both prior failure modes excluded:
//  - frag ds_reads issue BEFORE each phase barrier (latency absorbed at the
//    barrier; r8's exposed-latency bug fixed) and AFTER the previous iter's
//    vmcnt(4)+barrier residency checkpoint (r7's race fixed: reads of tile t
//    are in program order after the barrier that proved ALL waves' tile-t
//    loads complete).
//  - 3 LDS buffers (96 KB), staging runs 2 tiles ahead: tile t+1's loads get
//    a FULL iteration of slack before their checkpoint.
// 8 waves (2M x 4N), per-wave C 128x64 (acc 8x4 = 128 VGPR), BK=32.
// LDS slabs: slab s = rows s*16..+15 x 32 cols; lane l owns 16B chunk
// {row s*16+(l&15), cols (l>>4)*8..+7} at elem s*512+l*8 (conflict-free).
// Count audit: 4 loads/thread/tile (A 2 + B 2). Prologue: stage t0,t1 (8),
// vmcnt(4) -> t0 done. Iter t: ph0 stages A(t+2) (2), ph1 stages B(t+2) (2);
// end-of-iter vmcnt(4) leaves exactly t+2's 4 -> t+1 resident. Buffer
// (t+2)%3 written in iter t was read in iter t-1; its readers drained at
// t-1's lgkm(0) + end barrier.

struct Smem3 {
  alignas(16) bf16 A[3][256 * 32];
  alignas(16) bf16 B[3][256 * 32];
};

__device__ __forceinline__ void stage3(bf16* buf, const bf16* G, int ldg,
                                       int k0, int wave, int lane) {
  const int r16 = lane & 15, c8 = lane >> 4;
#pragma unroll
  for (int j = 0; j < 2; ++j) {
    int s = 2 * wave + j;
    gload16(G + (size_t)(s * 16 + r16) * ldg + k0 + c8 * 8,
            buf + s * 512 + lane * 8);
  }
}

__device__ __forceinline__ void gemm3_core(Smem3& sm, const bf16* A, int lda,
                                           const bf16* B, int ldb, int K,
                                           f32x4 acc[8][4]) {
  const int tid = threadIdx.x;
  const int wave = tid >> 6, lane = tid & 63;
  const int wr = wave >> 2, wc = wave & 3;
  const int NT = K >> 5;
  if (NT <= 0) return;

  stage3(sm.A[0], A, lda, 0, wave, lane);
  stage3(sm.B[0], B, ldb, 0, wave, lane);
  if (NT > 1) {
    stage3(sm.A[1], A, lda, 32, wave, lane);
    stage3(sm.B[1], B, ldb, 32, wave, lane);
    asm volatile("s_waitcnt vmcnt(4)" ::: "memory");  // tile 0 done (own)
  } else {
    asm volatile("s_waitcnt vmcnt(0)" ::: "memory");
  }
  __builtin_amdgcn_s_barrier();  // tile 0 resident for ALL waves

  const int abase = wr * 8 * 512 + lane * 8;  // A slabs wr*8..+7
  const int bbase = wc * 4 * 512 + lane * 8;  // B slabs wc*4..+3

  for (int t = 0; t < NT; ++t) {
    const bf16* Ab = sm.A[t % 3];
    const bf16* Bb = sm.B[t % 3];
    const bool pf = (t + 2 < NT);
    const int kn = (t + 2) * 32;
    const int nb = (t + 2) % 3;
    bf16x8 av[4], bv[4];

    // ---- phase 0: stage A(t+2); read bv + av(m0-3); barrier; MFMA ----
    if (pf) stage3(sm.A[nb], A, lda, kn, wave, lane);
#pragma unroll
    for (int nf = 0; nf < 4; ++nf) bv[nf] = *(const bf16x8*)&Bb[bbase + nf * 512];
#pragma unroll
    for (int mf = 0; mf < 4; ++mf) av[mf] = *(const bf16x8*)&Ab[abase + mf * 512];
    __builtin_amdgcn_s_barrier();
    asm volatile("s_waitcnt lgkmcnt(0)" ::: "memory");
    __builtin_amdgcn_sched_barrier(0);
    __builtin_amdgcn_s_setprio(1);
#pragma unroll
    for (int mf = 0; mf < 4; ++mf)
#pragma unroll
      for (int nf = 0; nf < 4; ++nf)
        acc[mf][nf] = __builtin_amdgcn_mfma_f32_16x16x32_bf16(av[mf], bv[nf],
                                                              acc[mf][nf], 0, 0, 0);
    __builtin_amdgcn_s_setprio(0);
    __builtin_amdgcn_s_barrier();

    // ---- phase 1: stage B(t+2); read av(m4-7); barrier; MFMA ----
    if (pf) stage3(sm.B[nb], B, ldb, kn, wave, lane);
#pragma unroll
    for (int mf = 0; mf < 4; ++mf)
      av[mf] = *(const bf16x8*)&Ab[abase + (mf + 4) * 512];
    __builtin_amdgcn_s_barrier();
    asm volatile("s_waitcnt lgkmcnt(0)" ::: "memory");
    __builtin_amdgcn_sched_barrier(0);
    __builtin_amdgcn_s_setprio(1);
#pragma unroll
    for (int mf = 0; mf < 4; ++mf)
#pragma unroll
      for (int nf = 0; nf < 4; ++nf)
        acc[mf + 4][nf] = __builtin_amdgcn_mfma_f32_16x16x32_bf16(av[mf], bv[nf],
                                                                  acc[mf + 4][nf], 0, 0, 0);
    __builtin_amdgcn_s_setprio(0);

    // ---- end-of-tile checkpoint: tile t+1 resident for all waves ----
    if (t + 1 < NT) {
      if (pf)
        asm volatile("s_waitcnt vmcnt(4)" ::: "memory");
      else
        asm volatile("s_waitcnt vmcnt(0)" ::: "memory");
      __builtin_amdgcn_s_barrier();
    }
  }
}

#define EPILOGUE256_VARS                           \
  const int lane = threadIdx.x & 63;               \
  const int wave = threadIdx.x >> 6;               \
  const int wr = wave >> 2, wc = wave & 3;         \
  const int l15 = lane & 15, kl = lane >> 4;

// ---------------- elementwise kernels ----------------

__global__ __launch_bounds__(256) void k_f2b(const float* __restrict__ in,
                                             bf16* __restrict__ out) {
  int i = (blockIdx.x * 256 + threadIdx.x) * 8;
  float4 a = *(const float4*)(in + i);
  float4 b = *(const float4*)(in + i + 4);
  bf16x8 o;
  o[0] = (bf16)a.x; o[1] = (bf16)a.y; o[2] = (bf16)a.z; o[3] = (bf16)a.w;
  o[4] = (bf16)b.x; o[5] = (bf16)b.y; o[6] = (bf16)b.z; o[7] = (bf16)b.w;
  *(bf16x8*)(out + i) = o;
}

// convert two 2048x2048 fp32 weights into one contiguous bf16 buffer
__global__ __launch_bounds__(256) void k_f2b2(const float* __restrict__ in0,
                                              const float* __restrict__ in1,
                                              bf16* __restrict__ out) {
  int i = (blockIdx.x * 256 + threadIdx.x) * 8;
  const float* src = (i < D_ * D_) ? in0 : in1;
  int off = (i < D_ * D_) ? i : i - D_ * D_;
  float4 a = *(const float4*)(src + off);
  float4 b = *(const float4*)(src + off + 4);
  bf16x8 o;
  o[0] = (bf16)a.x; o[1] = (bf16)a.y; o[2] = (bf16)a.z; o[3] = (bf16)a.w;
  o[4] = (bf16)b.x; o[5] = (bf16)b.y; o[6] = (bf16)b.z; o[7] = (bf16)b.w;
  *(bf16x8*)(out + i) = o;
}

__global__ __launch_bounds__(256) void k_rms(const float* __restrict__ x,
                                             bf16* __restrict__ xn) {
  const int row = blockIdx.x;
  const int tid = threadIdx.x;
  const float* xr = x + (size_t)row * D_;
  float4 a = *(const float4*)(xr + tid * 8);
  float4 b = *(const float4*)(xr + tid * 8 + 4);
  float ss = a.x * a.x + a.y * a.y + a.z * a.z + a.w * a.w +
             b.x * b.x + b.y * b.y + b.z * b.z + b.w * b.w;
#pragma unroll
  for (int o = 32; o > 0; o >>= 1) ss += __shfl_xor(ss, o, 64);
  __shared__ float red[4];
  if ((tid & 63) == 0) red[tid >> 6] = ss;
  __syncthreads();
  float tot = red[0] + red[1] + red[2] + red[3];
  float sc = rsqrtf(tot * (1.f / D_) + 1.1920928955078125e-07f);
  bf16x8 o;
  o[0] = (bf16)(a.x * sc); o[1] = (bf16)(a.y * sc);
  o[2] = (bf16)(a.z * sc); o[3] = (bf16)(a.w * sc);
  o[4] = (bf16)(b.x * sc); o[5] = (bf16)(b.y * sc);
  o[6] = (bf16)(b.z * sc); o[7] = (bf16)(b.w * sc);
  *(bf16x8*)(xn + (size_t)row * D_ + tid * 8) = o;
}

// ---------------- big dense GEMMs (256^2 ring core) ----------------
// grid (N/256=8, M/256=32) = 256 blocks -> 1 block/CU.

// C = act(xn @ W^T); SMODE bit0: store normal, bit1: store transposed [B][D][N]
template <int ACT, int SMODE>
__global__ __launch_bounds__(512, 2) void k_proj2(const bf16* __restrict__ xn,
                                                  const bf16* __restrict__ W,
                                                  bf16* __restrict__ Cn,
                                                  bf16* __restrict__ Ct) {
  __shared__ Smem3 sm;
  const int row0 = blockIdx.y * 256, col0 = blockIdx.x * 256;
  f32x4 acc[8][4] = {};
  gemm3_core(sm, xn + (size_t)row0 * D_, D_, W + (size_t)col0 * D_, D_, D_, acc);
  EPILOGUE256_VARS
#pragma unroll
  for (int mf = 0; mf < 8; ++mf)
#pragma unroll
    for (int nf = 0; nf < 4; ++nf)
#pragma unroll
      for (int j = 0; j < 4; ++j) {
        int r = row0 + wr * 128 + mf * 16 + kl * 4 + j;
        int c = col0 + wc * 64 + nf * 16 + l15;
        float v = acc[mf][nf][j];
        if (ACT == 1) v = v / (1.f + __expf(-v));        // silu
        if (ACT == 2) v = 1.f / (1.f + __expf(-v));      // sigmoid
        bf16 ob = (bf16)v;
        if (SMODE & 1) Cn[(size_t)r * D_ + c] = ob;
        if (SMODE & 2)
          Ct[((size_t)(r >> 12) * D_ + c) * NSEQ + (r & (NSEQ - 1))] = ob;
      }
}

// out = og @ Wp^T (fp32 store)
__global__ __launch_bounds__(512, 2) void k_final2(const bf16* __restrict__ og,
                                                   const bf16* __restrict__ Wp,
                                                   float* __restrict__ out) {
  __shared__ Smem3 sm;
  const int row0 = blockIdx.y * 256, col0 = blockIdx.x * 256;
  f32x4 acc[8][4] = {};
  gemm3_core(sm, og + (size_t)row0 * D_, D_, Wp + (size_t)col0 * D_, D_, D_, acc);
  EPILOGUE256_VARS
#pragma unroll
  for (int mf = 0; mf < 8; ++mf)
#pragma unroll
    for (int nf = 0; nf < 4; ++nf)
#pragma unroll
      for (int j = 0; j < 4; ++j) {
        int r = row0 + wr * 128 + mf * 16 + kl * 4 + j;
        int c = col0 + wc * 64 + nf * 16 + l15;
        out[(size_t)r * D_ + c] = acc[mf][nf][j];
      }
}

// ---------------- chunked-recurrence kernels (128^2 core) ----------------

// s[z] = tril(q_t k_t^T), z = b*TC + t, chunk CH=1024.
__global__ __launch_bounds__(256) void k_scores(const bf16* __restrict__ q,
                                                const bf16* __restrict__ k,
                                                bf16* __restrict__ s) {
  const int z = blockIdx.z, b = z >> 2, t = z & 3;
  const int row0 = blockIdx.y * 128, col0 = blockIdx.x * 128;
  if (col0 > row0) return;  // strictly upper tile
  __shared__ SmemTiles sm;
  f32x4 acc[4][4] = {};
  gemm_core(sm, q + (size_t)(b * NSEQ + t * CH + row0) * D_, D_,
                k + (size_t)(b * NSEQ + t * CH + col0) * D_, D_, D_, acc);
  EPILOGUE_VARS
  bf16* sp = s + (size_t)z * CH * CH;
#pragma unroll
  for (int m = 0; m < 4; ++m)
#pragma unroll
    for (int n = 0; n < 4; ++n)
#pragma unroll
      for (int j = 0; j < 4; ++j) {
        int i = row0 + wr * 64 + m * 16 + kl * 4 + j;
        int jc = col0 + wc * 64 + n * 16 + l15;
        float v = (i >= jc) ? acc[m][n][j] : 0.f;
        sp[(size_t)i * CH + jc] = (bf16)v;
      }
}

// og[chunk rows] = s @ v  (intra-chunk; K trimmed to lower-tri extent).
// Chunk 0 has no inter-chunk term, so its gate is applied HERE and
// k_ointer(t=0) is skipped entirely.
__global__ __launch_bounds__(256) void k_ointra(const bf16* __restrict__ s,
                                                const bf16* __restrict__ vT,
                                                const bf16* __restrict__ g,
                                                bf16* __restrict__ og) {
  __shared__ SmemTiles sm;
  const int z = blockIdx.z, b = z >> 2, t = z & 3;
  const int row0 = blockIdx.y * 128, col0 = blockIdx.x * 128;
  const int K = row0 + 128;
  f32x4 acc[4][4] = {};
  gemm_core(sm, s + (size_t)z * CH * CH + (size_t)row0 * CH, CH,
                vT + (size_t)b * D_ * NSEQ + (size_t)col0 * NSEQ + t * CH, NSEQ,
                K, acc);
  EPILOGUE_VARS
  const bool gate0 = (t == 0);
#pragma unroll
  for (int m = 0; m < 4; ++m)
#pragma unroll
    for (int n = 0; n < 4; ++n)
#pragma unroll
      for (int j = 0; j < 4; ++j) {
        int i = row0 + wr * 64 + m * 16 + kl * 4 + j;
        int c = col0 + wc * 64 + n * 16 + l15;
        size_t idx = (size_t)(b * NSEQ + t * CH + i) * D_ + c;
        float v = acc[m][n][j];
        if (gate0) v *= (float)g[idx];
        og[idx] = (bf16)v;
      }
}

// og = (og + q_t @ kvT^T) * g   for t >= 1
__global__ __launch_bounds__(256) void k_ointer(const bf16* __restrict__ q,
                                                const bf16* __restrict__ kvb,
                                                const bf16* __restrict__ g,
                                                bf16* __restrict__ og, int t) {
  __shared__ SmemTiles sm;
  const int b = blockIdx.z;
  const int row0 = blockIdx.y * 128, col0 = blockIdx.x * 128;
  f32x4 acc[4][4] = {};
  gemm_core(sm, q + (size_t)(b * NSEQ + t * CH + row0) * D_, D_,
                kvb + (size_t)b * D_ * D_ + (size_t)col0 * D_, D_, D_, acc);
  EPILOGUE_VARS
#pragma unroll
  for (int m = 0; m < 4; ++m)
#pragma unroll
    for (int n = 0; n < 4; ++n)
#pragma unroll
      for (int j = 0; j < 4; ++j) {
        int i = row0 + wr * 64 + m * 16 + kl * 4 + j;
        int c = col0 + wc * 64 + n * 16 + l15;
        size_t idx = (size_t)(b * NSEQ + t * CH + i) * D_ + c;
        float v = ((float)og[idx] + acc[m][n][j]) * (float)g[idx];
        og[idx] = (bf16)v;
      }
}

// kvT[b][e][d] += sum_{j in chunk t} v[j][e] k[j][d]  (bf16 accumulation;
// t==0 writes without reading so no memset/poison hazard)
__global__ __launch_bounds__(256) void k_update(const bf16* __restrict__ vT,
                                                const bf16* __restrict__ kT,
                                                bf16* __restrict__ kvb, int t) {
  __shared__ SmemTiles sm;
  const int b = blockIdx.z;
  const int row0 = blockIdx.y * 128, col0 = blockIdx.x * 128;
  f32x4 acc[4][4] = {};
  gemm_core(sm, vT + (size_t)b * D_ * NSEQ + (size_t)row0 * NSEQ + t * CH, NSEQ,
                kT + (size_t)b * D_ * NSEQ + (size_t)col0 * NSEQ + t * CH, NSEQ,
                CH, acc);
  EPILOGUE_VARS
#pragma unroll
  for (int m = 0; m < 4; ++m)
#pragma unroll
    for (int n = 0; n < 4; ++n)
#pragma unroll
      for (int j = 0; j < 4; ++j) {
        int e = row0 + wr * 64 + m * 16 + kl * 4 + j;
        int d = col0 + wc * 64 + n * 16 + l15;
        size_t idx = (size_t)b * D_ * D_ + (size_t)e * D_ + d;
        float v = acc[m][n][j];
        if (t > 0) v += (float)kvb[idx];
        kvb[idx] = (bf16)v;
      }
}

// ---------------- host launch ----------------
//
// Workspace plan (~145 MiB, proven R11): xn/og 32 | kT 32 | vT 32 | k 32 |
// shared 16.78 {Wpair -> s -> kvb -> Wpb}.
// q,g live in d_out (both dead before k_final2 overwrites it).

extern "C" void kernel_launch(void* const* d_in, const int* in_sizes, int n_in,
                              void* d_out, int out_size, void* d_ws, size_t ws_size,
                              hipStream_t stream) {
  (void)in_sizes; (void)n_in; (void)out_size; (void)ws_size;
  const float* x  = (const float*)d_in[0];
  const float* Wq = (const float*)d_in[1];
  const float* Wk = (const float*)d_in[2];
  const float* Wv = (const float*)d_in[3];
  const float* Wg = (const float*)d_in[4];
  const float* Wp = (const float*)d_in[5];
  float* out = (float*)d_out;

  char* p = (char*)d_ws;
  auto take = [&](size_t bytes) {
    char* r = p;
    p += (bytes + 255) & ~(size_t)255;
    return r;
  };
  const size_t MD2 = (size_t)MROWS * D_ * 2;

  bf16* xn  = (bf16*)take(MD2);                        // reused as og
  bf16* kT  = (bf16*)take(MD2);
  bf16* vT  = (bf16*)take(MD2);
  bf16* k   = (bf16*)take((size_t)MROWS * D_ * 2);     // scores operand
  char* shared = take((size_t)BATCH * TC * CH * CH * 2);  // 16.78 MiB region
  bf16* Wpair = (bf16*)shared;    // 2 weights (16 MiB), then s, then kvb, then Wp
  bf16* s    = (bf16*)shared;
  bf16* kvb  = (bf16*)shared;
  bf16* og = xn;

  bf16* q = (bf16*)d_out;
  bf16* g = (bf16*)d_out + (size_t)MROWS * D_;

  const size_t W1 = (size_t)D_ * D_;
  dim3 gp2(D_ / 256, MROWS / 256);  // (8, 32) = 256 blocks, 1/CU

  k_rms<<<MROWS, 256, 0, stream>>>(x, xn);

  k_f2b2<<<2 * (D_ * D_) / 2048, 256, 0, stream>>>(Wq, Wk, Wpair);
  k_proj2<1, 1><<<gp2, 512, 0, stream>>>(xn, Wpair, q, (bf16*)nullptr);
  k_proj2<1, 3><<<gp2, 512, 0, stream>>>(xn, Wpair + W1, k, kT);
  k_f2b2<<<2 * (D_ * D_) / 2048, 256, 0, stream>>>(Wv, Wg, Wpair);
  k_proj2<1, 2><<<gp2, 512, 0, stream>>>(xn, Wpair, (bf16*)nullptr, vT);
  k_proj2<2, 1><<<gp2, 512, 0, stream>>>(xn, Wpair + W1, g, (bf16*)nullptr);

  // intra-chunk: masked scores (lower-tri tiles only) then s @ v
  // (chunk 0 gated here; its k_ointer launch is skipped)
  k_scores<<<dim3(CH / 128, CH / 128, BATCH * TC), 256, 0, stream>>>(q, k, s);
  k_ointra<<<dim3(D_ / 128, CH / 128, BATCH * TC), 256, 0, stream>>>(s, vT, g, og);

  // s dead; region becomes the bf16 KV state (written by update t=0)
  for (int t = 1; t < TC; ++t) {
    k_update<<<dim3(D_ / 128, D_ / 128, BATCH), 256, 0, stream>>>(vT, kT,
                                                                  kvb, t - 1);
    k_ointer<<<dim3(D_ / 128, CH / 128, BATCH), 256, 0, stream>>>(q, kvb, g,
                                                                  og, t);
  }

  // kvb dead; region hosts the bf16 Wp
  bf16* Wpb = (bf16*)shared;
  k_f2b<<<(D_ * D_) / 2048, 256, 0, stream>>>(Wp, Wpb);
  k_final2<<<gp2, 512, 0, stream>>>(og, Wpb, out);
}

// Round 14
// 878.030 us; speedup vs baseline: 1.0528x; 1.0030x over previous
//
#include <hip/hip_runtime.h>
#include <hip/hip_bf16.h>

typedef __bf16 bf16;
typedef __bf16 bf16x8 __attribute__((ext_vector_type(8)));
typedef float f32x4 __attribute__((ext_vector_type(4)));
typedef unsigned int u32;

#define D_    2048
#define NSEQ  4096
#define BATCH 2
#define CH    1024   // recurrence chunk (math is chunk-size invariant)
#define TC    4      // chunks per batch
#define MROWS 8192   // BATCH*NSEQ

__device__ __forceinline__ void gload16(const bf16* g, bf16* l) {
  __builtin_amdgcn_global_load_lds(
      (const __attribute__((address_space(1))) u32*)g,
      (__attribute__((address_space(3))) u32*)l, 16, 0, 0);
}

// ============ 128^2 core, minimal 2-phase (recurrence kernels; proven) ======

struct SmemTiles {
  alignas(16) bf16 As[2][128 * 32];
  alignas(16) bf16 Bs[2][128 * 32];
};

__device__ __forceinline__ void stage128(SmemTiles& sm, int bb, const bf16* A,
                                         int lda, const bf16* B, int ldb,
                                         int k0, int tid) {
#pragma unroll
  for (int it = 0; it < 2; ++it) {
    int c = it * 256 + tid;      // 16B chunk index, 512 chunks per tile
    int r = c >> 2;              // 4 chunks per 32-elem row
    int co = (c & 3) << 3;
    gload16(A + (size_t)r * lda + k0 + co, &sm.As[bb][c * 8]);
    gload16(B + (size_t)r * ldb + k0 + co, &sm.Bs[bb][c * 8]);
  }
}

__device__ __forceinline__ void gemm_core(SmemTiles& sm, const bf16* A, int lda,
                                          const bf16* B, int ldb, int K,
                                          f32x4 acc[4][4]) {
  const int tid = threadIdx.x;
  const int lane = tid & 63;
  const int wave = tid >> 6;
  const int wr = wave >> 1, wc = wave & 1;
  const int l15 = lane & 15, kl = lane >> 4;
  const int NT = K >> 5;
  if (NT <= 0) return;

  stage128(sm, 0, A, lda, B, ldb, 0, tid);
  __syncthreads();

  const int ao = (wr * 64 + l15) * 32 + kl * 8;
  const int bo = (wc * 64 + l15) * 32 + kl * 8;

  for (int t = 0; t < NT; ++t) {
    if (t + 1 < NT)
      stage128(sm, (t + 1) & 1, A, lda, B, ldb, (t + 1) * 32, tid);
    const bf16* Ab = sm.As[t & 1];
    const bf16* Bb = sm.Bs[t & 1];
    bf16x8 a[4], b[4];
#pragma unroll
    for (int m = 0; m < 4; ++m) a[m] = *(const bf16x8*)(Ab + ao + m * 16 * 32);
#pragma unroll
    for (int n = 0; n < 4; ++n) b[n] = *(const bf16x8*)(Bb + bo + n * 16 * 32);
    __builtin_amdgcn_s_setprio(1);
#pragma unroll
    for (int m = 0; m < 4; ++m)
#pragma unroll
      for (int n = 0; n < 4; ++n)
        acc[m][n] = __builtin_amdgcn_mfma_f32_16x16x32_bf16(a[m], b[n], acc[m][n], 0, 0, 0);
    __builtin_amdgcn_s_setprio(0);
    if (t + 1 < NT) __syncthreads();
  }
}

#define EPILOGUE_VARS                              \
  const int lane = threadIdx.x & 63;               \
  const int wave = threadIdx.x >> 6;               \
  const int wr = wave >> 1, wc = wave & 1;         \
  const int l15 = lane & 15, kl = lane >> 4;

// ============ 256^2 big-GEMM core: 3-buffer ring, fine 2-phase/K-tile =======
//
// m201-pattern phases with both prior failure modes excluded:
//  - frag ds_reads issue BEFORE each phase barrier (latency absorbed at the
//    barrier; r8's exposed-latency bug fixed) and AFTER the previous iter's
//    vmcnt(4)+barrier residency checkpoint (r7's race fixed: reads of tile t
//    are in program order after the barrier that proved ALL waves' tile-t
//    loads complete).
//  - 3 LDS buffers (96 KB), staging runs 2 tiles ahead: tile t+1's loads get
//    a FULL iteration of slack before their checkpoint.
// 8 waves (2M x 4N), per-wave C 128x64 (acc 8x4 = 128 VGPR), BK=32.
// LDS slabs: slab s = rows s*16..+15 x 32 cols; lane l owns 16B chunk
// {row s*16+(l&15), cols (l>>4)*8..+7} at elem s*512+l*8 (conflict-free).
// Count audit: 4 loads/thread/tile (A 2 + B 2). Prologue: stage t0,t1 (8),
// vmcnt(4) -> t0 done. Iter t: ph0 stages A(t+2) (2), ph1 stages B(t+2) (2);
// end-of-iter vmcnt(4) leaves exactly t+2's 4 -> t+1 resident. Buffer
// (t+2)%3 written in iter t was read in iter t-1; its readers drained at
// t-1's lgkm(0) + end barrier.

struct Smem3 {
  alignas(16) bf16 A[3][256 * 32];
  alignas(16) bf16 B[3][256 * 32];
};

__device__ __forceinline__ void stage3(bf16* buf, const bf16* G, int ldg,
                                       int k0, int wave, int lane) {
  const int r16 = lane & 15, c8 = lane >> 4;
#pragma unroll
  for (int j = 0; j < 2; ++j) {
    int s = 2 * wave + j;
    gload16(G + (size_t)(s * 16 + r16) * ldg + k0 + c8 * 8,
            buf + s * 512 + lane * 8);
  }
}

__device__ __forceinline__ void gemm3_core(Smem3& sm, const bf16* A, int lda,
                                           const bf16* B, int ldb, int K,
                                           f32x4 acc[8][4]) {
  const int tid = threadIdx.x;
  const int wave = tid >> 6, lane = tid & 63;
  const int wr = wave >> 2, wc = wave & 3;
  const int NT = K >> 5;
  if (NT <= 0) return;

  stage3(sm.A[0], A, lda, 0, wave, lane);
  stage3(sm.B[0], B, ldb, 0, wave, lane);
  if (NT > 1) {
    stage3(sm.A[1], A, lda, 32, wave, lane);
    stage3(sm.B[1], B, ldb, 32, wave, lane);
    asm volatile("s_waitcnt vmcnt(4)" ::: "memory");  // tile 0 done (own)
  } else {
    asm volatile("s_waitcnt vmcnt(0)" ::: "memory");
  }
  __builtin_amdgcn_s_barrier();  // tile 0 resident for ALL waves

  const int abase = wr * 8 * 512 + lane * 8;  // A slabs wr*8..+7
  const int bbase = wc * 4 * 512 + lane * 8;  // B slabs wc*4..+3

  for (int t = 0; t < NT; ++t) {
    const bf16* Ab = sm.A[t % 3];
    const bf16* Bb = sm.B[t % 3];
    const bool pf = (t + 2 < NT);
    const int kn = (t + 2) * 32;
    const int nb = (t + 2) % 3;
    bf16x8 av[4], bv[4];

    // ---- phase 0: stage A(t+2); read bv + av(m0-3); barrier; MFMA ----
    if (pf) stage3(sm.A[nb], A, lda, kn, wave, lane);
#pragma unroll
    for (int nf = 0; nf < 4; ++nf) bv[nf] = *(const bf16x8*)&Bb[bbase + nf * 512];
#pragma unroll
    for (int mf = 0; mf < 4; ++mf) av[mf] = *(const bf16x8*)&Ab[abase + mf * 512];
    __builtin_amdgcn_s_barrier();
    asm volatile("s_waitcnt lgkmcnt(0)" ::: "memory");
    __builtin_amdgcn_sched_barrier(0);
    __builtin_amdgcn_s_setprio(1);
#pragma unroll
    for (int mf = 0; mf < 4; ++mf)
#pragma unroll
      for (int nf = 0; nf < 4; ++nf)
        acc[mf][nf] = __builtin_amdgcn_mfma_f32_16x16x32_bf16(av[mf], bv[nf],
                                                              acc[mf][nf], 0, 0, 0);
    __builtin_amdgcn_s_setprio(0);
    __builtin_amdgcn_s_barrier();

    // ---- phase 1: stage B(t+2); read av(m4-7); barrier; MFMA ----
    if (pf) stage3(sm.B[nb], B, ldb, kn, wave, lane);
#pragma unroll
    for (int mf = 0; mf < 4; ++mf)
      av[mf] = *(const bf16x8*)&Ab[abase + (mf + 4) * 512];
    __builtin_amdgcn_s_barrier();
    asm volatile("s_waitcnt lgkmcnt(0)" ::: "memory");
    __builtin_amdgcn_sched_barrier(0);
    __builtin_amdgcn_s_setprio(1);
#pragma unroll
    for (int mf = 0; mf < 4; ++mf)
#pragma unroll
      for (int nf = 0; nf < 4; ++nf)
        acc[mf + 4][nf] = __builtin_amdgcn_mfma_f32_16x16x32_bf16(av[mf], bv[nf],
                                                                  acc[mf + 4][nf], 0, 0, 0);
    __builtin_amdgcn_s_setprio(0);

    // ---- end-of-tile checkpoint: tile t+1 resident for all waves ----
    if (t + 1 < NT) {
      if (pf)
        asm volatile("s_waitcnt vmcnt(4)" ::: "memory");
      else
        asm volatile("s_waitcnt vmcnt(0)" ::: "memory");
      __builtin_amdgcn_s_barrier();
    }
  }
}

#define EPILOGUE256_VARS                           \
  const int lane = threadIdx.x & 63;               \
  const int wave = threadIdx.x >> 6;               \
  const int wr = wave >> 2, wc = wave & 3;         \
  const int l15 = lane & 15, kl = lane >> 4;

// ---------------- elementwise kernels ----------------

__global__ __launch_bounds__(256) void k_f2b(const float* __restrict__ in,
                                             bf16* __restrict__ out) {
  int i = (blockIdx.x * 256 + threadIdx.x) * 8;
  float4 a = *(const float4*)(in + i);
  float4 b = *(const float4*)(in + i + 4);
  bf16x8 o;
  o[0] = (bf16)a.x; o[1] = (bf16)a.y; o[2] = (bf16)a.z; o[3] = (bf16)a.w;
  o[4] = (bf16)b.x; o[5] = (bf16)b.y; o[6] = (bf16)b.z; o[7] = (bf16)b.w;
  *(bf16x8*)(out + i) = o;
}

// convert two 2048x2048 fp32 weights into one contiguous bf16 buffer
__global__ __launch_bounds__(256) void k_f2b2(const float* __restrict__ in0,
                                              const float* __restrict__ in1,
                                              bf16* __restrict__ out) {
  int i = (blockIdx.x * 256 + threadIdx.x) * 8;
  const float* src = (i < D_ * D_) ? in0 : in1;
  int off = (i < D_ * D_) ? i : i - D_ * D_;
  float4 a = *(const float4*)(src + off);
  float4 b = *(const float4*)(src + off + 4);
  bf16x8 o;
  o[0] = (bf16)a.x; o[1] = (bf16)a.y; o[2] = (bf16)a.z; o[3] = (bf16)a.w;
  o[4] = (bf16)b.x; o[5] = (bf16)b.y; o[6] = (bf16)b.z; o[7] = (bf16)b.w;
  *(bf16x8*)(out + i) = o;
}

__global__ __launch_bounds__(256) void k_rms(const float* __restrict__ x,
                                             bf16* __restrict__ xn) {
  const int row = blockIdx.x;
  const int tid = threadIdx.x;
  const float* xr = x + (size_t)row * D_;
  float4 a = *(const float4*)(xr + tid * 8);
  float4 b = *(const float4*)(xr + tid * 8 + 4);
  float ss = a.x * a.x + a.y * a.y + a.z * a.z + a.w * a.w +
             b.x * b.x + b.y * b.y + b.z * b.z + b.w * b.w;
#pragma unroll
  for (int o = 32; o > 0; o >>= 1) ss += __shfl_xor(ss, o, 64);
  __shared__ float red[4];
  if ((tid & 63) == 0) red[tid >> 6] = ss;
  __syncthreads();
  float tot = red[0] + red[1] + red[2] + red[3];
  float sc = rsqrtf(tot * (1.f / D_) + 1.1920928955078125e-07f);
  bf16x8 o;
  o[0] = (bf16)(a.x * sc); o[1] = (bf16)(a.y * sc);
  o[2] = (bf16)(a.z * sc); o[3] = (bf16)(a.w * sc);
  o[4] = (bf16)(b.x * sc); o[5] = (bf16)(b.y * sc);
  o[6] = (bf16)(b.z * sc); o[7] = (bf16)(b.w * sc);
  *(bf16x8*)(xn + (size_t)row * D_ + tid * 8) = o;
}

// ---------------- big dense GEMMs (256^2 ring core) ----------------
// grid (N/256=8, M/256=32) = 256 blocks -> 1 block/CU.

// C = act(xn @ W^T); SMODE bit0: store normal, bit1: store transposed [B][D][N]
template <int ACT, int SMODE>
__global__ __launch_bounds__(512, 2) void k_proj2(const bf16* __restrict__ xn,
                                                  const bf16* __restrict__ W,
                                                  bf16* __restrict__ Cn,
                                                  bf16* __restrict__ Ct) {
  __shared__ Smem3 sm;
  const int row0 = blockIdx.y * 256, col0 = blockIdx.x * 256;
  f32x4 acc[8][4] = {};
  gemm3_core(sm, xn + (size_t)row0 * D_, D_, W + (size_t)col0 * D_, D_, D_, acc);
  EPILOGUE256_VARS
#pragma unroll
  for (int mf = 0; mf < 8; ++mf)
#pragma unroll
    for (int nf = 0; nf < 4; ++nf)
#pragma unroll
      for (int j = 0; j < 4; ++j) {
        int r = row0 + wr * 128 + mf * 16 + kl * 4 + j;
        int c = col0 + wc * 64 + nf * 16 + l15;
        float v = acc[mf][nf][j];
        if (ACT == 1) v = v / (1.f + __expf(-v));        // silu
        if (ACT == 2) v = 1.f / (1.f + __expf(-v));      // sigmoid
        bf16 ob = (bf16)v;
        if (SMODE & 1) Cn[(size_t)r * D_ + c] = ob;
        if (SMODE & 2)
          Ct[((size_t)(r >> 12) * D_ + c) * NSEQ + (r & (NSEQ - 1))] = ob;
      }
}

// out = og @ Wp^T (fp32 store)
__global__ __launch_bounds__(512, 2) void k_final2(const bf16* __restrict__ og,
                                                   const bf16* __restrict__ Wp,
                                                   float* __restrict__ out) {
  __shared__ Smem3 sm;
  const int row0 = blockIdx.y * 256, col0 = blockIdx.x * 256;
  f32x4 acc[8][4] = {};
  gemm3_core(sm, og + (size_t)row0 * D_, D_, Wp + (size_t)col0 * D_, D_, D_, acc);
  EPILOGUE256_VARS
#pragma unroll
  for (int mf = 0; mf < 8; ++mf)
#pragma unroll
    for (int nf = 0; nf < 4; ++nf)
#pragma unroll
      for (int j = 0; j < 4; ++j) {
        int r = row0 + wr * 128 + mf * 16 + kl * 4 + j;
        int c = col0 + wc * 64 + nf * 16 + l15;
        out[(size_t)r * D_ + c] = acc[mf][nf][j];
      }
}

// ---------------- chunked-recurrence kernels (128^2 core) ----------------

// s[z] = tril(q_t k_t^T), z = b*TC + t, chunk CH=1024.
__global__ __launch_bounds__(256) void k_scores(const bf16* __restrict__ q,
                                                const bf16* __restrict__ k,
                                                bf16* __restrict__ s) {
  const int z = blockIdx.z, b = z >> 2, t = z & 3;
  const int row0 = blockIdx.y * 128, col0 = blockIdx.x * 128;
  if (col0 > row0) return;  // strictly upper tile
  __shared__ SmemTiles sm;
  f32x4 acc[4][4] = {};
  gemm_core(sm, q + (size_t)(b * NSEQ + t * CH + row0) * D_, D_,
                k + (size_t)(b * NSEQ + t * CH + col0) * D_, D_, D_, acc);
  EPILOGUE_VARS
  bf16* sp = s + (size_t)z * CH * CH;
#pragma unroll
  for (int m = 0; m < 4; ++m)
#pragma unroll
    for (int n = 0; n < 4; ++n)
#pragma unroll
      for (int j = 0; j < 4; ++j) {
        int i = row0 + wr * 64 + m * 16 + kl * 4 + j;
        int jc = col0 + wc * 64 + n * 16 + l15;
        float v = (i >= jc) ? acc[m][n][j] : 0.f;
        sp[(size_t)i * CH + jc] = (bf16)v;
      }
}

// og[chunk rows] = s @ v  (intra-chunk; K trimmed to lower-tri extent).
// Chunk 0 has no inter-chunk term, so its gate is applied HERE and
// k_ointer(t=0) is skipped entirely.
__global__ __launch_bounds__(256) void k_ointra(const bf16* __restrict__ s,
                                                const bf16* __restrict__ vT,
                                                const bf16* __restrict__ g,
                                                bf16* __restrict__ og) {
  __shared__ SmemTiles sm;
  const int z = blockIdx.z, b = z >> 2, t = z & 3;
  const int row0 = blockIdx.y * 128, col0 = blockIdx.x * 128;
  const int K = row0 + 128;
  f32x4 acc[4][4] = {};
  gemm_core(sm, s + (size_t)z * CH * CH + (size_t)row0 * CH, CH,
                vT + (size_t)b * D_ * NSEQ + (size_t)col0 * NSEQ + t * CH, NSEQ,
                K, acc);
  EPILOGUE_VARS
  const bool gate0 = (t == 0);
#pragma unroll
  for (int m = 0; m < 4; ++m)
#pragma unroll
    for (int n = 0; n < 4; ++n)
#pragma unroll
      for (int j = 0; j < 4; ++j) {
        int i = row0 + wr * 64 + m * 16 + kl * 4 + j;
        int c = col0 + wc * 64 + n * 16 + l15;
        size_t idx = (size_t)(b * NSEQ + t * CH + i) * D_ + c;
        float v = acc[m][n][j];
        if (gate0) v *= (float)g[idx];
        og[idx] = (bf16)v;
      }
}

// og = (og + q_t @ kvT^T) * g   for t >= 1
__global__ __launch_bounds__(256) void k_ointer(const bf16* __restrict__ q,
                                                const bf16* __restrict__ kvb,
                                                const bf16* __restrict__ g,
                                                bf16* __restrict__ og, int t) {
  __shared__ SmemTiles sm;
  const int b = blockIdx.z;
  const int row0 = blockIdx.y * 128, col0 = blockIdx.x * 128;
  f32x4 acc[4][4] = {};
  gemm_core(sm, q + (size_t)(b * NSEQ + t * CH + row0) * D_, D_,
                kvb + (size_t)b * D_ * D_ + (size_t)col0 * D_, D_, D_, acc);
  EPILOGUE_VARS
#pragma unroll
  for (int m = 0; m < 4; ++m)
#pragma unroll
    for (int n = 0; n < 4; ++n)
#pragma unroll
      for (int j = 0; j < 4; ++j) {
        int i = row0 + wr * 64 + m * 16 + kl * 4 + j;
        int c = col0 + wc * 64 + n * 16 + l15;
        size_t idx = (size_t)(b * NSEQ + t * CH + i) * D_ + c;
        float v = ((float)og[idx] + acc[m][n][j]) * (float)g[idx];
        og[idx] = (bf16)v;
      }
}

// kvT[b][e][d] += sum_{j in chunk t} v[j][e] k[j][d]  (bf16 accumulation;
// t==0 writes without reading so no memset/poison hazard)
__global__ __launch_bounds__(256) void k_update(const bf16* __restrict__ vT,
                                                const bf16* __restrict__ kT,
                                                bf16* __restrict__ kvb, int t) {
  __shared__ SmemTiles sm;
  const int b = blockIdx.z;
  const int row0 = blockIdx.y * 128, col0 = blockIdx.x * 128;
  f32x4 acc[4][4] = {};
  gemm_core(sm, vT + (size_t)b * D_ * NSEQ + (size_t)row0 * NSEQ + t * CH, NSEQ,
                kT + (size_t)b * D_ * NSEQ + (size_t)col0 * NSEQ + t * CH, NSEQ,
                CH, acc);
  EPILOGUE_VARS
#pragma unroll
  for (int m = 0; m < 4; ++m)
#pragma unroll
    for (int n = 0; n < 4; ++n)
#pragma unroll
      for (int j = 0; j < 4; ++j) {
        int e = row0 + wr * 64 + m * 16 + kl * 4 + j;
        int d = col0 + wc * 64 + n * 16 + l15;
        size_t idx = (size_t)b * D_ * D_ + (size_t)e * D_ + d;
        float v = acc[m][n][j];
        if (t > 0) v += (float)kvb[idx];
        kvb[idx] = (bf16)v;
      }
}

// ---------------- host launch ----------------
//
// Workspace plan (~145 MiB, proven R11): xn/og 32 | kT 32 | vT 32 | k 32 |
// shared 16.78 {Wpair -> s -> kvb -> Wpb}.
// q,g live in d_out (both dead before k_final2 overwrites it).

extern "C" void kernel_launch(void* const* d_in, const int* in_sizes, int n_in,
                              void* d_out, int out_size, void* d_ws, size_t ws_size,
                              hipStream_t stream) {
  (void)in_sizes; (void)n_in; (void)out_size; (void)ws_size;
  const float* x  = (const float*)d_in[0];
  const float* Wq = (const float*)d_in[1];
  const float* Wk = (const float*)d_in[2];
  const float* Wv = (const float*)d_in[3];
  const float* Wg = (const float*)d_in[4];
  const float* Wp = (const float*)d_in[5];
  float* out = (float*)d_out;

  char* p = (char*)d_ws;
  auto take = [&](size_t bytes) {
    char* r = p;
    p += (bytes + 255) & ~(size_t)255;
    return r;
  };
  const size_t MD2 = (size_t)MROWS * D_ * 2;

  bf16* xn  = (bf16*)take(MD2);                        // reused as og
  bf16* kT  = (bf16*)take(MD2);
  bf16* vT  = (bf16*)take(MD2);
  bf16* k   = (bf16*)take((size_t)MROWS * D_ * 2);     // scores operand
  char* shared = take((size_t)BATCH * TC * CH * CH * 2);  // 16.78 MiB region
  bf16* Wpair = (bf16*)shared;    // 2 weights (16 MiB), then s, then kvb, then Wp
  bf16* s    = (bf16*)shared;
  bf16* kvb  = (bf16*)shared;
  bf16* og = xn;

  bf16* q = (bf16*)d_out;
  bf16* g = (bf16*)d_out + (size_t)MROWS * D_;

  const size_t W1 = (size_t)D_ * D_;
  dim3 gp2(D_ / 256, MROWS / 256);  // (8, 32) = 256 blocks, 1/CU

  k_rms<<<MROWS, 256, 0, stream>>>(x, xn);

  k_f2b2<<<2 * (D_ * D_) / 2048, 256, 0, stream>>>(Wq, Wk, Wpair);
  k_proj2<1, 1><<<gp2, 512, 0, stream>>>(xn, Wpair, q, (bf16*)nullptr);
  k_proj2<1, 3><<<gp2, 512, 0, stream>>>(xn, Wpair + W1, k, kT);
  k_f2b2<<<2 * (D_ * D_) / 2048, 256, 0, stream>>>(Wv, Wg, Wpair);
  k_proj2<1, 2><<<gp2, 512, 0, stream>>>(xn, Wpair, (bf16*)nullptr, vT);
  k_proj2<2, 1><<<gp2, 512, 0, stream>>>(xn, Wpair + W1, g, (bf16*)nullptr);

  // intra-chunk: masked scores (lower-tri tiles only) then s @ v
  // (chunk 0 gated here; its k_ointer launch is skipped)
  k_scores<<<dim3(CH / 128, CH / 128, BATCH * TC), 256, 0, stream>>>(q, k, s);
  k_ointra<<<dim3(D_ / 128, CH / 128, BATCH * TC), 256, 0, stream>>>(s, vT, g, og);

  // s dead; region becomes the bf16 KV state (written by update t=0)
  for (int t = 1; t < TC; ++t) {
    k_update<<<dim3(D_ / 128, D_ / 128, BATCH), 256, 0, stream>>>(vT, kT,
                                                                  kvb, t - 1);
    k_ointer<<<dim3(D_ / 128, CH / 128, BATCH), 256, 0, stream>>>(q, kvb, g,
                                                                  og, t);
  }

  // kvb dead; region hosts the bf16 Wp
  bf16* Wpb = (bf16*)shared;
  k_f2b<<<(D_ * D_) / 2048, 256, 0, stream>>>(Wp, Wpb);
  k_final2<<<gp2, 512, 0, stream>>>(og, Wpb, out);
}

// Round 15
// 847.000 us; speedup vs baseline: 1.0914x; 1.0366x over previous
//
#include <hip/hip_runtime.h>
#include <hip/hip_bf16.h>

typedef __bf16 bf16;
typedef __bf16 bf16x4 __attribute__((ext_vector_type(4)));
typedef __bf16 bf16x8 __attribute__((ext_vector_type(8)));
typedef float f32x4 __attribute__((ext_vector_type(4)));
typedef unsigned int u32;

#define D_    2048
#define NSEQ  4096
#define BATCH 2
#define CH    1024   // recurrence chunk (math is chunk-size invariant)
#define TC    4      // chunks per batch
#define MROWS 8192   // BATCH*NSEQ

__device__ __forceinline__ void gload16(const bf16* g, bf16* l) {
  __builtin_amdgcn_global_load_lds(
      (const __attribute__((address_space(1))) u32*)g,
      (__attribute__((address_space(3))) u32*)l, 16, 0, 0);
}

// ============ 128^2 core, minimal 2-phase (recurrence kernels; proven) ======

struct SmemTiles {
  alignas(16) bf16 As[2][128 * 32];
  alignas(16) bf16 Bs[2][128 * 32];
};

__device__ __forceinline__ void stage128(SmemTiles& sm, int bb, const bf16* A,
                                         int lda, const bf16* B, int ldb,
                                         int k0, int tid) {
#pragma unroll
  for (int it = 0; it < 2; ++it) {
    int c = it * 256 + tid;      // 16B chunk index, 512 chunks per tile
    int r = c >> 2;              // 4 chunks per 32-elem row
    int co = (c & 3) << 3;
    gload16(A + (size_t)r * lda + k0 + co, &sm.As[bb][c * 8]);
    gload16(B + (size_t)r * ldb + k0 + co, &sm.Bs[bb][c * 8]);
  }
}

__device__ __forceinline__ void gemm_core(SmemTiles& sm, const bf16* A, int lda,
                                          const bf16* B, int ldb, int K,
                                          f32x4 acc[4][4]) {
  const int tid = threadIdx.x;
  const int lane = tid & 63;
  const int wave = tid >> 6;
  const int wr = wave >> 1, wc = wave & 1;
  const int l15 = lane & 15, kl = lane >> 4;
  const int NT = K >> 5;
  if (NT <= 0) return;

  stage128(sm, 0, A, lda, B, ldb, 0, tid);
  __syncthreads();

  const int ao = (wr * 64 + l15) * 32 + kl * 8;
  const int bo = (wc * 64 + l15) * 32 + kl * 8;

  for (int t = 0; t < NT; ++t) {
    if (t + 1 < NT)
      stage128(sm, (t + 1) & 1, A, lda, B, ldb, (t + 1) * 32, tid);
    const bf16* Ab = sm.As[t & 1];
    const bf16* Bb = sm.Bs[t & 1];
    bf16x8 a[4], b[4];
#pragma unroll
    for (int m = 0; m < 4; ++m) a[m] = *(const bf16x8*)(Ab + ao + m * 16 * 32);
#pragma unroll
    for (int n = 0; n < 4; ++n) b[n] = *(const bf16x8*)(Bb + bo + n * 16 * 32);
    __builtin_amdgcn_s_setprio(1);
#pragma unroll
    for (int m = 0; m < 4; ++m)
#pragma unroll
      for (int n = 0; n < 4; ++n)
        acc[m][n] = __builtin_amdgcn_mfma_f32_16x16x32_bf16(a[m], b[n], acc[m][n], 0, 0, 0);
    __builtin_amdgcn_s_setprio(0);
    if (t + 1 < NT) __syncthreads();
  }
}

#define EPILOGUE_VARS                              \
  const int lane = threadIdx.x & 63;               \
  const int wave = threadIdx.x >> 6;               \
  const int wr = wave >> 1, wc = wave & 1;         \
  const int l15 = lane & 15, kl = lane >> 4;

// ============ 128x256 big-GEMM core: counted-vmcnt 2-deep (R11, proven) =====

struct SmemW {
  alignas(16) bf16 A[2][128 * 32];   // 8 slabs x 512 elems per buffer
  alignas(16) bf16 B[2][256 * 32];   // 16 slabs per buffer
};

__device__ __forceinline__ void stageW(SmemW& sm, int bb, const bf16* A,
                                       int lda, const bf16* B, int ldb,
                                       int k0, int wave, int lane) {
  const int r16 = lane & 15, c8 = lane >> 4;
  gload16(A + (size_t)(wave * 16 + r16) * lda + k0 + c8 * 8,
          &sm.A[bb][wave * 512 + lane * 8]);
#pragma unroll
  for (int j = 0; j < 2; ++j) {
    int nb = 2 * wave + j;
    gload16(B + (size_t)(nb * 16 + r16) * ldb + k0 + c8 * 8,
            &sm.B[bb][nb * 512 + lane * 8]);
  }
}

__device__ __forceinline__ void gemmW_core(SmemW& sm, const bf16* A, int lda,
                                           const bf16* B, int ldb, int K,
                                           f32x4 acc[4][4]) {
  const int tid = threadIdx.x;
  const int wave = tid >> 6, lane = tid & 63;
  const int wr = wave >> 2, wc = wave & 3;
  const int NT = K >> 5;
  if (NT <= 0) return;

  stageW(sm, 0, A, lda, B, ldb, 0, wave, lane);
  if (NT > 1) {
    stageW(sm, 1, A, lda, B, ldb, 32, wave, lane);
    asm volatile("s_waitcnt vmcnt(3)" ::: "memory");  // tile 0 resident (own)
  } else {
    asm volatile("s_waitcnt vmcnt(0)" ::: "memory");
  }
  __builtin_amdgcn_s_barrier();  // tile 0 resident for ALL waves

  const int aoff = wr * 2048 + lane * 8;  // slabs wr*4..+3
  const int boff = wc * 2048 + lane * 8;  // slabs wc*4..+3

  for (int t = 0; t < NT; ++t) {
    const bf16* Ab = sm.A[t & 1];
    const bf16* Bb = sm.B[t & 1];
    bf16x8 av[4], bv[4];
#pragma unroll
    for (int m = 0; m < 4; ++m) av[m] = *(const bf16x8*)&Ab[aoff + m * 512];
#pragma unroll
    for (int n = 0; n < 4; ++n) bv[n] = *(const bf16x8*)&Bb[boff + n * 512];
    asm volatile("s_waitcnt lgkmcnt(0)" ::: "memory");  // my reads done
    __builtin_amdgcn_s_barrier();                       // all waves' reads done
    if (t + 2 < NT)                                     // refill freed buffer
      stageW(sm, t & 1, A, lda, B, ldb, (t + 2) * 32, wave, lane);
    __builtin_amdgcn_s_setprio(1);
#pragma unroll
    for (int m = 0; m < 4; ++m)
#pragma unroll
      for (int n = 0; n < 4; ++n)
        acc[m][n] = __builtin_amdgcn_mfma_f32_16x16x32_bf16(av[m], bv[n],
                                                            acc[m][n], 0, 0, 0);
    __builtin_amdgcn_s_setprio(0);
    if (t + 1 < NT) {
      if (t + 2 < NT)
        asm volatile("s_waitcnt vmcnt(3)" ::: "memory");  // t+1 resident
      else
        asm volatile("s_waitcnt vmcnt(0)" ::: "memory");
      __builtin_amdgcn_s_barrier();
    }
  }
}

#define EPILOGUEW_VARS                             \
  const int lane = threadIdx.x & 63;               \
  const int wave = threadIdx.x >> 6;               \
  const int wr = wave >> 2, wc = wave & 3;         \
  const int l15 = lane & 15, kl = lane >> 4;

// T1: bijective XCD row-chunk swizzle for the (8, 64) big-GEMM grids.
// Default dispatch round-robins XCD by lin%8; remap so XCD i owns
// by in [8i, 8i+8) x all bx -> A working set 8 x 0.5 MB = 4 MB = one L2.
// (R8 measured FETCH 135 -> 49 MB with this family of swizzle.)
__device__ __forceinline__ void swzW(int& bx, int& by) {
  int lin = blockIdx.y * gridDim.x + blockIdx.x;   // 0..511
  int xcd = lin & 7, pos = lin >> 3;               // pos 0..63
  by = xcd * 8 + (pos >> 3);
  bx = pos & 7;
}

// ---------------- elementwise kernels ----------------

__global__ __launch_bounds__(256) void k_f2b(const float* __restrict__ in,
                                             bf16* __restrict__ out) {
  int i = (blockIdx.x * 256 + threadIdx.x) * 8;
  float4 a = *(const float4*)(in + i);
  float4 b = *(const float4*)(in + i + 4);
  bf16x8 o;
  o[0] = (bf16)a.x; o[1] = (bf16)a.y; o[2] = (bf16)a.z; o[3] = (bf16)a.w;
  o[4] = (bf16)b.x; o[5] = (bf16)b.y; o[6] = (bf16)b.z; o[7] = (bf16)b.w;
  *(bf16x8*)(out + i) = o;
}

// convert two 2048x2048 fp32 weights into one contiguous bf16 buffer
__global__ __launch_bounds__(256) void k_f2b2(const float* __restrict__ in0,
                                              const float* __restrict__ in1,
                                              bf16* __restrict__ out) {
  int i = (blockIdx.x * 256 + threadIdx.x) * 8;
  const float* src = (i < D_ * D_) ? in0 : in1;
  int off = (i < D_ * D_) ? i : i - D_ * D_;
  float4 a = *(const float4*)(src + off);
  float4 b = *(const float4*)(src + off + 4);
  bf16x8 o;
  o[0] = (bf16)a.x; o[1] = (bf16)a.y; o[2] = (bf16)a.z; o[3] = (bf16)a.w;
  o[4] = (bf16)b.x; o[5] = (bf16)b.y; o[6] = (bf16)b.z; o[7] = (bf16)b.w;
  *(bf16x8*)(out + i) = o;
}

__global__ __launch_bounds__(256) void k_rms(const float* __restrict__ x,
                                             bf16* __restrict__ xn) {
  const int row = blockIdx.x;
  const int tid = threadIdx.x;
  const float* xr = x + (size_t)row * D_;
  float4 a = *(const float4*)(xr + tid * 8);
  float4 b = *(const float4*)(xr + tid * 8 + 4);
  float ss = a.x * a.x + a.y * a.y + a.z * a.z + a.w * a.w +
             b.x * b.x + b.y * b.y + b.z * b.z + b.w * b.w;
#pragma unroll
  for (int o = 32; o > 0; o >>= 1) ss += __shfl_xor(ss, o, 64);
  __shared__ float red[4];
  if ((tid & 63) == 0) red[tid >> 6] = ss;
  __syncthreads();
  float tot = red[0] + red[1] + red[2] + red[3];
  float sc = rsqrtf(tot * (1.f / D_) + 1.1920928955078125e-07f);
  bf16x8 o;
  o[0] = (bf16)(a.x * sc); o[1] = (bf16)(a.y * sc);
  o[2] = (bf16)(a.z * sc); o[3] = (bf16)(a.w * sc);
  o[4] = (bf16)(b.x * sc); o[5] = (bf16)(b.y * sc);
  o[6] = (bf16)(b.z * sc); o[7] = (bf16)(b.w * sc);
  *(bf16x8*)(xn + (size_t)row * D_ + tid * 8) = o;
}

// ---------------- big dense GEMMs (128x256 W-core + XCD swizzle) ------------
// grid (N/256=8, M/128=64) = 512 blocks -> 2 resident/CU.

// C = act(xn @ W^T); SMODE bit0: store normal, bit1: store transposed [B][D][N]
// Transposed store: j-axis (4 consecutive rows) is contiguous in Ct -> one
// packed 8B bf16x4 store per (m,n) instead of 4 scattered 2B stores.
template <int ACT, int SMODE>
__global__ __launch_bounds__(512, 4) void k_proj2(const bf16* __restrict__ xn,
                                                  const bf16* __restrict__ W,
                                                  bf16* __restrict__ Cn,
                                                  bf16* __restrict__ Ct) {
  __shared__ SmemW sm;
  int bx, by;
  swzW(bx, by);
  const int row0 = by * 128, col0 = bx * 256;
  f32x4 acc[4][4] = {};
  gemmW_core(sm, xn + (size_t)row0 * D_, D_, W + (size_t)col0 * D_, D_, D_, acc);
  EPILOGUEW_VARS
#pragma unroll
  for (int m = 0; m < 4; ++m)
#pragma unroll
    for (int n = 0; n < 4; ++n) {
      const int rb = row0 + wr * 64 + m * 16 + kl * 4;  // 4 consecutive rows
      const int c = col0 + wc * 64 + n * 16 + l15;
      bf16 ob[4];
#pragma unroll
      for (int j = 0; j < 4; ++j) {
        float v = acc[m][n][j];
        if (ACT == 1) v = v / (1.f + __expf(-v));        // silu
        if (ACT == 2) v = 1.f / (1.f + __expf(-v));      // sigmoid
        ob[j] = (bf16)v;
      }
      if (SMODE & 1) {
#pragma unroll
        for (int j = 0; j < 4; ++j) Cn[(size_t)(rb + j) * D_ + c] = ob[j];
      }
      if (SMODE & 2) {
        bf16x4 tv = {ob[0], ob[1], ob[2], ob[3]};
        *(bf16x4*)&Ct[((size_t)(rb >> 12) * D_ + c) * NSEQ + (rb & (NSEQ - 1))] = tv;
      }
    }
}

// out = og @ Wp^T (fp32 store)
__global__ __launch_bounds__(512, 4) void k_final2(const bf16* __restrict__ og,
                                                   const bf16* __restrict__ Wp,
                                                   float* __restrict__ out) {
  __shared__ SmemW sm;
  int bx, by;
  swzW(bx, by);
  const int row0 = by * 128, col0 = bx * 256;
  f32x4 acc[4][4] = {};
  gemmW_core(sm, og + (size_t)row0 * D_, D_, Wp + (size_t)col0 * D_, D_, D_, acc);
  EPILOGUEW_VARS
#pragma unroll
  for (int m = 0; m < 4; ++m)
#pragma unroll
    for (int n = 0; n < 4; ++n)
#pragma unroll
      for (int j = 0; j < 4; ++j) {
        int r = row0 + wr * 64 + m * 16 + kl * 4 + j;
        int c = col0 + wc * 64 + n * 16 + l15;
        out[(size_t)r * D_ + c] = acc[m][n][j];
      }
}

// ---------------- chunked-recurrence kernels (128^2 core) ----------------

// s[z] = tril(q_t k_t^T), z = b*TC + t, chunk CH=1024.
__global__ __launch_bounds__(256) void k_scores(const bf16* __restrict__ q,
                                                const bf16* __restrict__ k,
                                                bf16* __restrict__ s) {
  const int z = blockIdx.z, b = z >> 2, t = z & 3;
  const int row0 = blockIdx.y * 128, col0 = blockIdx.x * 128;
  if (col0 > row0) return;  // strictly upper tile
  __shared__ SmemTiles sm;
  f32x4 acc[4][4] = {};
  gemm_core(sm, q + (size_t)(b * NSEQ + t * CH + row0) * D_, D_,
                k + (size_t)(b * NSEQ + t * CH + col0) * D_, D_, D_, acc);
  EPILOGUE_VARS
  bf16* sp = s + (size_t)z * CH * CH;
#pragma unroll
  for (int m = 0; m < 4; ++m)
#pragma unroll
    for (int n = 0; n < 4; ++n)
#pragma unroll
      for (int j = 0; j < 4; ++j) {
        int i = row0 + wr * 64 + m * 16 + kl * 4 + j;
        int jc = col0 + wc * 64 + n * 16 + l15;
        float v = (i >= jc) ? acc[m][n][j] : 0.f;
        sp[(size_t)i * CH + jc] = (bf16)v;
      }
}

// og[chunk rows] = s @ v  (intra-chunk; K trimmed to lower-tri extent).
// Chunk 0 has no inter-chunk term, so its gate is applied HERE and
// k_ointer(t=0) is skipped entirely.
__global__ __launch_bounds__(256) void k_ointra(const bf16* __restrict__ s,
                                                const bf16* __restrict__ vT,
                                                const bf16* __restrict__ g,
                                                bf16* __restrict__ og) {
  __shared__ SmemTiles sm;
  const int z = blockIdx.z, b = z >> 2, t = z & 3;
  const int row0 = blockIdx.y * 128, col0 = blockIdx.x * 128;
  const int K = row0 + 128;
  f32x4 acc[4][4] = {};
  gemm_core(sm, s + (size_t)z * CH * CH + (size_t)row0 * CH, CH,
                vT + (size_t)b * D_ * NSEQ + (size_t)col0 * NSEQ + t * CH, NSEQ,
                K, acc);
  EPILOGUE_VARS
  const bool gate0 = (t == 0);
#pragma unroll
  for (int m = 0; m < 4; ++m)
#pragma unroll
    for (int n = 0; n < 4; ++n)
#pragma unroll
      for (int j = 0; j < 4; ++j) {
        int i = row0 + wr * 64 + m * 16 + kl * 4 + j;
        int c = col0 + wc * 64 + n * 16 + l15;
        size_t idx = (size_t)(b * NSEQ + t * CH + i) * D_ + c;
        float v = acc[m][n][j];
        if (gate0) v *= (float)g[idx];
        og[idx] = (bf16)v;
      }
}

// og = (og + q_t @ kvT^T) * g   for t >= 1
__global__ __launch_bounds__(256) void k_ointer(const bf16* __restrict__ q,
                                                const bf16* __restrict__ kvb,
                                                const bf16* __restrict__ g,
                                                bf16* __restrict__ og, int t) {
  __shared__ SmemTiles sm;
  const int b = blockIdx.z;
  const int row0 = blockIdx.y * 128, col0 = blockIdx.x * 128;
  f32x4 acc[4][4] = {};
  gemm_core(sm, q + (size_t)(b * NSEQ + t * CH + row0) * D_, D_,
                kvb + (size_t)b * D_ * D_ + (size_t)col0 * D_, D_, D_, acc);
  EPILOGUE_VARS
#pragma unroll
  for (int m = 0; m < 4; ++m)
#pragma unroll
    for (int n = 0; n < 4; ++n)
#pragma unroll
      for (int j = 0; j < 4; ++j) {
        int i = row0 + wr * 64 + m * 16 + kl * 4 + j;
        int c = col0 + wc * 64 + n * 16 + l15;
        size_t idx = (size_t)(b * NSEQ + t * CH + i) * D_ + c;
        float v = ((float)og[idx] + acc[m][n][j]) * (float)g[idx];
        og[idx] = (bf16)v;
      }
}

// kvT[b][e][d] += sum_{j in chunk t} v[j][e] k[j][d]  (bf16 accumulation;
// t==0 writes without reading so no memset/poison hazard)
__global__ __launch_bounds__(256) void k_update(const bf16* __restrict__ vT,
                                                const bf16* __restrict__ kT,
                                                bf16* __restrict__ kvb, int t) {
  __shared__ SmemTiles sm;
  const int b = blockIdx.z;
  const int row0 = blockIdx.y * 128, col0 = blockIdx.x * 128;
  f32x4 acc[4][4] = {};
  gemm_core(sm, vT + (size_t)b * D_ * NSEQ + (size_t)row0 * NSEQ + t * CH, NSEQ,
                kT + (size_t)b * D_ * NSEQ + (size_t)col0 * NSEQ + t * CH, NSEQ,
                CH, acc);
  EPILOGUE_VARS
#pragma unroll
  for (int m = 0; m < 4; ++m)
#pragma unroll
    for (int n = 0; n < 4; ++n)
#pragma unroll
      for (int j = 0; j < 4; ++j) {
        int e = row0 + wr * 64 + m * 16 + kl * 4 + j;
        int d = col0 + wc * 64 + n * 16 + l15;
        size_t idx = (size_t)b * D_ * D_ + (size_t)e * D_ + d;
        float v = acc[m][n][j];
        if (t > 0) v += (float)kvb[idx];
        kvb[idx] = (bf16)v;
      }
}

// ---------------- host launch ----------------
//
// Workspace plan (~145 MiB, proven R11): xn/og 32 | kT 32 | vT 32 | k 32 |
// shared 16.78 {Wpair -> s -> kvb -> Wpb}.
// q,g live in d_out (both dead before k_final2 overwrites it).

extern "C" void kernel_launch(void* const* d_in, const int* in_sizes, int n_in,
                              void* d_out, int out_size, void* d_ws, size_t ws_size,
                              hipStream_t stream) {
  (void)in_sizes; (void)n_in; (void)out_size; (void)ws_size;
  const float* x  = (const float*)d_in[0];
  const float* Wq = (const float*)d_in[1];
  const float* Wk = (const float*)d_in[2];
  const float* Wv = (const float*)d_in[3];
  const float* Wg = (const float*)d_in[4];
  const float* Wp = (const float*)d_in[5];
  float* out = (float*)d_out;

  char* p = (char*)d_ws;
  auto take = [&](size_t bytes) {
    char* r = p;
    p += (bytes + 255) & ~(size_t)255;
    return r;
  };
  const size_t MD2 = (size_t)MROWS * D_ * 2;

  bf16* xn  = (bf16*)take(MD2);                        // reused as og
  bf16* kT  = (bf16*)take(MD2);
  bf16* vT  = (bf16*)take(MD2);
  bf16* k   = (bf16*)take((size_t)MROWS * D_ * 2);     // scores operand
  char* shared = take((size_t)BATCH * TC * CH * CH * 2);  // 16.78 MiB region
  bf16* Wpair = (bf16*)shared;    // 2 weights (16 MiB), then s, then kvb, then Wp
  bf16* s    = (bf16*)shared;
  bf16* kvb  = (bf16*)shared;
  bf16* og = xn;

  bf16* q = (bf16*)d_out;
  bf16* g = (bf16*)d_out + (size_t)MROWS * D_;

  const size_t W1 = (size_t)D_ * D_;
  dim3 gpW(D_ / 256, MROWS / 128);  // (8, 64) = 512 blocks, 2/CU

  k_rms<<<MROWS, 256, 0, stream>>>(x, xn);

  k_f2b2<<<2 * (D_ * D_) / 2048, 256, 0, stream>>>(Wq, Wk, Wpair);
  k_proj2<1, 1><<<gpW, 512, 0, stream>>>(xn, Wpair, q, (bf16*)nullptr);
  k_proj2<1, 3><<<gpW, 512, 0, stream>>>(xn, Wpair + W1, k, kT);
  k_f2b2<<<2 * (D_ * D_) / 2048, 256, 0, stream>>>(Wv, Wg, Wpair);
  k_proj2<1, 2><<<gpW, 512, 0, stream>>>(xn, Wpair, (bf16*)nullptr, vT);
  k_proj2<2, 1><<<gpW, 512, 0, stream>>>(xn, Wpair + W1, g, (bf16*)nullptr);

  // intra-chunk: masked scores (lower-tri tiles only) then s @ v
  // (chunk 0 gated here; its k_ointer launch is skipped)
  k_scores<<<dim3(CH / 128, CH / 128, BATCH * TC), 256, 0, stream>>>(q, k, s);
  k_ointra<<<dim3(D_ / 128, CH / 128, BATCH * TC), 256, 0, stream>>>(s, vT, g, og);

  // s dead; region becomes the bf16 KV state (written by update t=0)
  for (int t = 1; t < TC; ++t) {
    k_update<<<dim3(D_ / 128, D_ / 128, BATCH), 256, 0, stream>>>(vT, kT,
                                                                  kvb, t - 1);
    k_ointer<<<dim3(D_ / 128, CH / 128, BATCH), 256, 0, stream>>>(q, kvb, g,
                                                                  og, t);
  }

  // kvb dead; region hosts the bf16 Wp
  bf16* Wpb = (bf16*)shared;
  k_f2b<<<(D_ * D_) / 2048, 256, 0, stream>>>(Wp, Wpb);
  k_final2<<<gpW, 512, 0, stream>>>(og, Wpb, out);
}

// Round 16
// 769.063 us; speedup vs baseline: 1.2020x; 1.1013x over previous
//
#include <hip/hip_runtime.h>
#include <hip/hip_bf16.h>

typedef __bf16 bf16;
typedef __bf16 bf16x4 __attribute__((ext_vector_type(4)));
typedef __bf16 bf16x8 __attribute__((ext_vector_type(8)));
typedef float f32x4 __attribute__((ext_vector_type(4)));
typedef unsigned int u32;

#define D_    2048
#define NSEQ  4096
#define BATCH 2
#define CH    1024   // recurrence chunk (math is chunk-size invariant)
#define TC    4      // chunks per batch
#define MROWS 8192   // BATCH*NSEQ

__device__ __forceinline__ void gload16(const bf16* g, bf16* l) {
  __builtin_amdgcn_global_load_lds(
      (const __attribute__((address_space(1))) u32*)g,
      (__attribute__((address_space(3))) u32*)l, 16, 0, 0);
}

// ============ 128^2 core, minimal 2-phase (recurrence kernels; proven) ======

struct SmemTiles {
  alignas(16) bf16 As[2][128 * 32];
  alignas(16) bf16 Bs[2][128 * 32];
};

__device__ __forceinline__ void stage128(SmemTiles& sm, int bb, const bf16* A,
                                         int lda, const bf16* B, int ldb,
                                         int k0, int tid) {
#pragma unroll
  for (int it = 0; it < 2; ++it) {
    int c = it * 256 + tid;      // 16B chunk index, 512 chunks per tile
    int r = c >> 2;              // 4 chunks per 32-elem row
    int co = (c & 3) << 3;
    gload16(A + (size_t)r * lda + k0 + co, &sm.As[bb][c * 8]);
    gload16(B + (size_t)r * ldb + k0 + co, &sm.Bs[bb][c * 8]);
  }
}

__device__ __forceinline__ void gemm_core(SmemTiles& sm, const bf16* A, int lda,
                                          const bf16* B, int ldb, int K,
                                          f32x4 acc[4][4]) {
  const int tid = threadIdx.x;
  const int lane = tid & 63;
  const int wave = tid >> 6;
  const int wr = wave >> 1, wc = wave & 1;
  const int l15 = lane & 15, kl = lane >> 4;
  const int NT = K >> 5;
  if (NT <= 0) return;

  stage128(sm, 0, A, lda, B, ldb, 0, tid);
  __syncthreads();

  const int ao = (wr * 64 + l15) * 32 + kl * 8;
  const int bo = (wc * 64 + l15) * 32 + kl * 8;

  for (int t = 0; t < NT; ++t) {
    if (t + 1 < NT)
      stage128(sm, (t + 1) & 1, A, lda, B, ldb, (t + 1) * 32, tid);
    const bf16* Ab = sm.As[t & 1];
    const bf16* Bb = sm.Bs[t & 1];
    bf16x8 a[4], b[4];
#pragma unroll
    for (int m = 0; m < 4; ++m) a[m] = *(const bf16x8*)(Ab + ao + m * 16 * 32);
#pragma unroll
    for (int n = 0; n < 4; ++n) b[n] = *(const bf16x8*)(Bb + bo + n * 16 * 32);
    __builtin_amdgcn_s_setprio(1);
#pragma unroll
    for (int m = 0; m < 4; ++m)
#pragma unroll
      for (int n = 0; n < 4; ++n)
        acc[m][n] = __builtin_amdgcn_mfma_f32_16x16x32_bf16(a[m], b[n], acc[m][n], 0, 0, 0);
    __builtin_amdgcn_s_setprio(0);
    if (t + 1 < NT) __syncthreads();
  }
}

#define EPILOGUE_VARS                              \
  const int lane = threadIdx.x & 63;               \
  const int wave = threadIdx.x >> 6;               \
  const int wr = wave >> 1, wc = wave & 1;         \
  const int l15 = lane & 15, kl = lane >> 4;

// ============ 128x256 big-GEMM core: counted-vmcnt 2-deep (R11, proven) =====

struct SmemW {
  alignas(16) bf16 A[2][128 * 32];   // 8 slabs x 512 elems per buffer
  alignas(16) bf16 B[2][256 * 32];   // 16 slabs per buffer
};

__device__ __forceinline__ void stageW(SmemW& sm, int bb, const bf16* A,
                                       int lda, const bf16* B, int ldb,
                                       int k0, int wave, int lane) {
  const int r16 = lane & 15, c8 = lane >> 4;
  gload16(A + (size_t)(wave * 16 + r16) * lda + k0 + c8 * 8,
          &sm.A[bb][wave * 512 + lane * 8]);
#pragma unroll
  for (int j = 0; j < 2; ++j) {
    int nb = 2 * wave + j;
    gload16(B + (size_t)(nb * 16 + r16) * ldb + k0 + c8 * 8,
            &sm.B[bb][nb * 512 + lane * 8]);
  }
}

__device__ __forceinline__ void gemmW_core(SmemW& sm, const bf16* A, int lda,
                                           const bf16* B, int ldb, int K,
                                           f32x4 acc[4][4]) {
  const int tid = threadIdx.x;
  const int wave = tid >> 6, lane = tid & 63;
  const int wr = wave >> 2, wc = wave & 3;
  const int NT = K >> 5;
  if (NT <= 0) return;

  stageW(sm, 0, A, lda, B, ldb, 0, wave, lane);
  if (NT > 1) {
    stageW(sm, 1, A, lda, B, ldb, 32, wave, lane);
    asm volatile("s_waitcnt vmcnt(3)" ::: "memory");  // tile 0 resident (own)
  } else {
    asm volatile("s_waitcnt vmcnt(0)" ::: "memory");
  }
  __builtin_amdgcn_s_barrier();  // tile 0 resident for ALL waves

  const int aoff = wr * 2048 + lane * 8;  // slabs wr*4..+3
  const int boff = wc * 2048 + lane * 8;  // slabs wc*4..+3

  for (int t = 0; t < NT; ++t) {
    const bf16* Ab = sm.A[t & 1];
    const bf16* Bb = sm.B[t & 1];
    bf16x8 av[4], bv[4];
#pragma unroll
    for (int m = 0; m < 4; ++m) av[m] = *(const bf16x8*)&Ab[aoff + m * 512];
#pragma unroll
    for (int n = 0; n < 4; ++n) bv[n] = *(const bf16x8*)&Bb[boff + n * 512];
    asm volatile("s_waitcnt lgkmcnt(0)" ::: "memory");  // my reads done
    __builtin_amdgcn_s_barrier();                       // all waves' reads done
    if (t + 2 < NT)                                     // refill freed buffer
      stageW(sm, t & 1, A, lda, B, ldb, (t + 2) * 32, wave, lane);
    __builtin_amdgcn_s_setprio(1);
#pragma unroll
    for (int m = 0; m < 4; ++m)
#pragma unroll
      for (int n = 0; n < 4; ++n)
        acc[m][n] = __builtin_amdgcn_mfma_f32_16x16x32_bf16(av[m], bv[n],
                                                            acc[m][n], 0, 0, 0);
    __builtin_amdgcn_s_setprio(0);
    if (t + 1 < NT) {
      if (t + 2 < NT)
        asm volatile("s_waitcnt vmcnt(3)" ::: "memory");  // t+1 resident
      else
        asm volatile("s_waitcnt vmcnt(0)" ::: "memory");
      __builtin_amdgcn_s_barrier();
    }
  }
}

#define EPILOGUEW_VARS                             \
  const int lane = threadIdx.x & 63;               \
  const int wave = threadIdx.x >> 6;               \
  const int wr = wave >> 2, wc = wave & 3;         \
  const int l15 = lane & 15, kl = lane >> 4;

// T1: bijective XCD row-chunk swizzle for the (8, 64) big-GEMM grids.
// XCD i owns by in [8i, 8i+8) x all bx -> A working set 4 MB = one L2.
// (R15 measured: FETCH 135 -> 76 MB, dur 137 -> 116 us.)
__device__ __forceinline__ void swzW(int& bx, int& by) {
  int lin = blockIdx.y * gridDim.x + blockIdx.x;   // 0..511
  int xcd = lin & 7, pos = lin >> 3;               // pos 0..63
  by = xcd * 8 + (pos >> 3);
  bx = pos & 7;
}

// ---------------- elementwise kernels ----------------

__global__ __launch_bounds__(256) void k_f2b(const float* __restrict__ in,
                                             bf16* __restrict__ out) {
  int i = (blockIdx.x * 256 + threadIdx.x) * 8;
  float4 a = *(const float4*)(in + i);
  float4 b = *(const float4*)(in + i + 4);
  bf16x8 o;
  o[0] = (bf16)a.x; o[1] = (bf16)a.y; o[2] = (bf16)a.z; o[3] = (bf16)a.w;
  o[4] = (bf16)b.x; o[5] = (bf16)b.y; o[6] = (bf16)b.z; o[7] = (bf16)b.w;
  *(bf16x8*)(out + i) = o;
}

// convert two 2048x2048 fp32 weights into one contiguous bf16 buffer
__global__ __launch_bounds__(256) void k_f2b2(const float* __restrict__ in0,
                                              const float* __restrict__ in1,
                                              bf16* __restrict__ out) {
  int i = (blockIdx.x * 256 + threadIdx.x) * 8;
  const float* src = (i < D_ * D_) ? in0 : in1;
  int off = (i < D_ * D_) ? i : i - D_ * D_;
  float4 a = *(const float4*)(src + off);
  float4 b = *(const float4*)(src + off + 4);
  bf16x8 o;
  o[0] = (bf16)a.x; o[1] = (bf16)a.y; o[2] = (bf16)a.z; o[3] = (bf16)a.w;
  o[4] = (bf16)b.x; o[5] = (bf16)b.y; o[6] = (bf16)b.z; o[7] = (bf16)b.w;
  *(bf16x8*)(out + i) = o;
}

// dst += src (bf16, fp32 add), 8 elems/thread
__global__ __launch_bounds__(256) void k_add(bf16* __restrict__ dst,
                                             const bf16* __restrict__ src) {
  size_t i = ((size_t)blockIdx.x * 256 + threadIdx.x) * 8;
  bf16x8 a = *(const bf16x8*)(dst + i);
  bf16x8 b = *(const bf16x8*)(src + i);
  bf16x8 o;
#pragma unroll
  for (int j = 0; j < 8; ++j) o[j] = (bf16)((float)a[j] + (float)b[j]);
  *(bf16x8*)(dst + i) = o;
}

__global__ __launch_bounds__(256) void k_rms(const float* __restrict__ x,
                                             bf16* __restrict__ xn) {
  const int row = blockIdx.x;
  const int tid = threadIdx.x;
  const float* xr = x + (size_t)row * D_;
  float4 a = *(const float4*)(xr + tid * 8);
  float4 b = *(const float4*)(xr + tid * 8 + 4);
  float ss = a.x * a.x + a.y * a.y + a.z * a.z + a.w * a.w +
             b.x * b.x + b.y * b.y + b.z * b.z + b.w * b.w;
#pragma unroll
  for (int o = 32; o > 0; o >>= 1) ss += __shfl_xor(ss, o, 64);
  __shared__ float red[4];
  if ((tid & 63) == 0) red[tid >> 6] = ss;
  __syncthreads();
  float tot = red[0] + red[1] + red[2] + red[3];
  float sc = rsqrtf(tot * (1.f / D_) + 1.1920928955078125e-07f);
  bf16x8 o;
  o[0] = (bf16)(a.x * sc); o[1] = (bf16)(a.y * sc);
  o[2] = (bf16)(a.z * sc); o[3] = (bf16)(a.w * sc);
  o[4] = (bf16)(b.x * sc); o[5] = (bf16)(b.y * sc);
  o[6] = (bf16)(b.z * sc); o[7] = (bf16)(b.w * sc);
  *(bf16x8*)(xn + (size_t)row * D_ + tid * 8) = o;
}

// ---------------- big dense GEMMs (128x256 W-core + XCD swizzle) ------------
// grid (N/256=8, M/128=64) = 512 blocks -> 2 resident/CU.

// C = act(xn @ W^T); SMODE bit0: store normal, bit1: store transposed [B][D][N]
template <int ACT, int SMODE>
__global__ __launch_bounds__(512, 4) void k_proj2(const bf16* __restrict__ xn,
                                                  const bf16* __restrict__ W,
                                                  bf16* __restrict__ Cn,
                                                  bf16* __restrict__ Ct) {
  __shared__ SmemW sm;
  int bx, by;
  swzW(bx, by);
  const int row0 = by * 128, col0 = bx * 256;
  f32x4 acc[4][4] = {};
  gemmW_core(sm, xn + (size_t)row0 * D_, D_, W + (size_t)col0 * D_, D_, D_, acc);
  EPILOGUEW_VARS
#pragma unroll
  for (int m = 0; m < 4; ++m)
#pragma unroll
    for (int n = 0; n < 4; ++n) {
      const int rb = row0 + wr * 64 + m * 16 + kl * 4;  // 4 consecutive rows
      const int c = col0 + wc * 64 + n * 16 + l15;
      bf16 ob[4];
#pragma unroll
      for (int j = 0; j < 4; ++j) {
        float v = acc[m][n][j];
        if (ACT == 1) v = v / (1.f + __expf(-v));        // silu
        if (ACT == 2) v = 1.f / (1.f + __expf(-v));      // sigmoid
        ob[j] = (bf16)v;
      }
      if (SMODE & 1) {
#pragma unroll
        for (int j = 0; j < 4; ++j) Cn[(size_t)(rb + j) * D_ + c] = ob[j];
      }
      if (SMODE & 2) {
        bf16x4 tv = {ob[0], ob[1], ob[2], ob[3]};
        *(bf16x4*)&Ct[((size_t)(rb >> 12) * D_ + c) * NSEQ + (rb & (NSEQ - 1))] = tv;
      }
    }
}

// out = og @ Wp^T (fp32 store)
__global__ __launch_bounds__(512, 4) void k_final2(const bf16* __restrict__ og,
                                                   const bf16* __restrict__ Wp,
                                                   float* __restrict__ out) {
  __shared__ SmemW sm;
  int bx, by;
  swzW(bx, by);
  const int row0 = by * 128, col0 = bx * 256;
  f32x4 acc[4][4] = {};
  gemmW_core(sm, og + (size_t)row0 * D_, D_, Wp + (size_t)col0 * D_, D_, D_, acc);
  EPILOGUEW_VARS
#pragma unroll
  for (int m = 0; m < 4; ++m)
#pragma unroll
    for (int n = 0; n < 4; ++n)
#pragma unroll
      for (int j = 0; j < 4; ++j) {
        int r = row0 + wr * 64 + m * 16 + kl * 4 + j;
        int c = col0 + wc * 64 + n * 16 + l15;
        out[(size_t)r * D_ + c] = acc[m][n][j];
      }
}

// ---------------- chunked-recurrence kernels (128^2 core) ----------------

// s[z] = tril(q_t k_t^T), z = b*TC + t, chunk CH=1024.
__global__ __launch_bounds__(256) void k_scores(const bf16* __restrict__ q,
                                                const bf16* __restrict__ k,
                                                bf16* __restrict__ s) {
  const int z = blockIdx.z, b = z >> 2, t = z & 3;
  const int row0 = blockIdx.y * 128, col0 = blockIdx.x * 128;
  if (col0 > row0) return;  // strictly upper tile
  __shared__ SmemTiles sm;
  f32x4 acc[4][4] = {};
  gemm_core(sm, q + (size_t)(b * NSEQ + t * CH + row0) * D_, D_,
                k + (size_t)(b * NSEQ + t * CH + col0) * D_, D_, D_, acc);
  EPILOGUE_VARS
  bf16* sp = s + (size_t)z * CH * CH;
#pragma unroll
  for (int m = 0; m < 4; ++m)
#pragma unroll
    for (int n = 0; n < 4; ++n)
#pragma unroll
      for (int j = 0; j < 4; ++j) {
        int i = row0 + wr * 64 + m * 16 + kl * 4 + j;
        int jc = col0 + wc * 64 + n * 16 + l15;
        float v = (i >= jc) ? acc[m][n][j] : 0.f;
        sp[(size_t)i * CH + jc] = (bf16)v;
      }
}

// og[chunk rows] = s @ v  (intra-chunk; K trimmed to lower-tri extent).
// Chunk 0 has no inter-chunk term, so its gate is applied HERE and
// the inter-chunk pass skips t=0 entirely.
__global__ __launch_bounds__(256) void k_ointra(const bf16* __restrict__ s,
                                                const bf16* __restrict__ vT,
                                                const bf16* __restrict__ g,
                                                bf16* __restrict__ og) {
  __shared__ SmemTiles sm;
  const int z = blockIdx.z, b = z >> 2, t = z & 3;
  const int row0 = blockIdx.y * 128, col0 = blockIdx.x * 128;
  const int K = row0 + 128;
  f32x4 acc[4][4] = {};
  gemm_core(sm, s + (size_t)z * CH * CH + (size_t)row0 * CH, CH,
                vT + (size_t)b * D_ * NSEQ + (size_t)col0 * NSEQ + t * CH, NSEQ,
                K, acc);
  EPILOGUE_VARS
  const bool gate0 = (t == 0);
#pragma unroll
  for (int m = 0; m < 4; ++m)
#pragma unroll
    for (int n = 0; n < 4; ++n)
#pragma unroll
      for (int j = 0; j < 4; ++j) {
        int i = row0 + wr * 64 + m * 16 + kl * 4 + j;
        int c = col0 + wc * 64 + n * 16 + l15;
        size_t idx = (size_t)(b * NSEQ + t * CH + i) * D_ + c;
        float v = acc[m][n][j];
        if (gate0) v *= (float)g[idx];
        og[idx] = (bf16)v;
      }
}

// ALL per-chunk outer products in one parallel launch (pure write):
// kv_s[b][e][d] = sum_{j in chunk s} v[j][e] k[j][d], s in {0,1,2}, b in {0,1}.
// Slots: s<2 -> kv01 + (s*2+b)*D^2 ; s==2 -> kv2 + b*D^2.
__global__ __launch_bounds__(256) void k_update_all(const bf16* __restrict__ vT,
                                                    const bf16* __restrict__ kT,
                                                    bf16* __restrict__ kv01,
                                                    bf16* __restrict__ kv2) {
  __shared__ SmemTiles sm;
  const int z = blockIdx.z, s = z >> 1, b = z & 1;
  const int row0 = blockIdx.y * 128, col0 = blockIdx.x * 128;  // row=e, col=d
  f32x4 acc[4][4] = {};
  gemm_core(sm, vT + (size_t)b * D_ * NSEQ + (size_t)row0 * NSEQ + s * CH, NSEQ,
                kT + (size_t)b * D_ * NSEQ + (size_t)col0 * NSEQ + s * CH, NSEQ,
                CH, acc);
  EPILOGUE_VARS
  bf16* dst = (s < 2) ? kv01 + (size_t)(s * 2 + b) * D_ * D_
                      : kv2 + (size_t)b * D_ * D_;
#pragma unroll
  for (int m = 0; m < 4; ++m)
#pragma unroll
    for (int n = 0; n < 4; ++n)
#pragma unroll
      for (int j = 0; j < 4; ++j) {
        int e = row0 + wr * 64 + m * 16 + kl * 4 + j;
        int d = col0 + wc * 64 + n * 16 + l15;
        dst[(size_t)e * D_ + d] = (bf16)acc[m][n][j];
      }
}

// og = (og + q_t @ prefix_{t-1}^T) * g  for all t in {1,2,3}, both batches,
// one parallel launch. prefix slots (after in-place k_add prefix sums):
// t=1 -> kv01+b*D^2 ; t=2 -> kv01+(2+b)*D^2 ; t=3 -> kv2+b*D^2.
__global__ __launch_bounds__(256) void k_ointer_all(const bf16* __restrict__ q,
                                                    const bf16* __restrict__ kv01,
                                                    const bf16* __restrict__ kv2,
                                                    const bf16* __restrict__ g,
                                                    bf16* __restrict__ og) {
  __shared__ SmemTiles sm;
  const int z = blockIdx.z;             // 0..5
  const int t = (z >> 1) + 1, b = z & 1;
  const bf16* kv = (t <= 2) ? kv01 + (size_t)((t - 1) * 2 + b) * D_ * D_
                            : kv2 + (size_t)b * D_ * D_;
  const int row0 = blockIdx.y * 128, col0 = blockIdx.x * 128;
  f32x4 acc[4][4] = {};
  gemm_core(sm, q + (size_t)(b * NSEQ + t * CH + row0) * D_, D_,
                kv + (size_t)col0 * D_, D_, D_, acc);
  EPILOGUE_VARS
#pragma unroll
  for (int m = 0; m < 4; ++m)
#pragma unroll
    for (int n = 0; n < 4; ++n)
#pragma unroll
      for (int j = 0; j < 4; ++j) {
        int i = row0 + wr * 64 + m * 16 + kl * 4 + j;
        int c = col0 + wc * 64 + n * 16 + l15;
        size_t idx = (size_t)(b * NSEQ + t * CH + i) * D_ + c;
        float v = ((float)og[idx] + acc[m][n][j]) * (float)g[idx];
        og[idx] = (bf16)v;
      }
}

// ---------------- host launch ----------------
//
// Workspace plan (~145 MiB, proven): xn/og 32 | kT 32 | vT 32 |
// {k 32 -> kv01 32 (4 slots, EXACT fit)} | shared 16 {Wpair -> s ->
// kv2 (2 slots, EXACT fit) -> Wpb}.  q,g live in d_out.
// Parallel recurrence: scores/ointra -> update_all (kv0,kv1,kv2 parallel,
// pure write) -> 2 prefix adds -> ointer_all (all 3 chunks parallel).

extern "C" void kernel_launch(void* const* d_in, const int* in_sizes, int n_in,
                              void* d_out, int out_size, void* d_ws, size_t ws_size,
                              hipStream_t stream) {
  (void)in_sizes; (void)n_in; (void)out_size; (void)ws_size;
  const float* x  = (const float*)d_in[0];
  const float* Wq = (const float*)d_in[1];
  const float* Wk = (const float*)d_in[2];
  const float* Wv = (const float*)d_in[3];
  const float* Wg = (const float*)d_in[4];
  const float* Wp = (const float*)d_in[5];
  float* out = (float*)d_out;

  char* p = (char*)d_ws;
  auto take = [&](size_t bytes) {
    char* r = p;
    p += (bytes + 255) & ~(size_t)255;
    return r;
  };
  const size_t MD2 = (size_t)MROWS * D_ * 2;
  const size_t KV1 = (size_t)D_ * D_;          // elems per kv slot

  bf16* xn  = (bf16*)take(MD2);                        // reused as og
  bf16* kT  = (bf16*)take(MD2);
  bf16* vT  = (bf16*)take(MD2);
  char* kregion = take(MD2);                           // k, then kv01 (4 slots)
  bf16* k    = (bf16*)kregion;
  bf16* kv01 = (bf16*)kregion;
  char* shared = take((size_t)BATCH * TC * CH * CH * 2);  // 16 MiB region
  bf16* Wpair = (bf16*)shared;    // 2 weights, then s, then kv2 (2 slots), then Wp
  bf16* s    = (bf16*)shared;
  bf16* kv2  = (bf16*)shared;
  bf16* og = xn;

  bf16* q = (bf16*)d_out;
  bf16* g = (bf16*)d_out + (size_t)MROWS * D_;

  const size_t W1 = (size_t)D_ * D_;
  dim3 gpW(D_ / 256, MROWS / 128);  // (8, 64) = 512 blocks, 2/CU

  k_rms<<<MROWS, 256, 0, stream>>>(x, xn);

  k_f2b2<<<2 * (D_ * D_) / 2048, 256, 0, stream>>>(Wq, Wk, Wpair);
  k_proj2<1, 1><<<gpW, 512, 0, stream>>>(xn, Wpair, q, (bf16*)nullptr);
  k_proj2<1, 3><<<gpW, 512, 0, stream>>>(xn, Wpair + W1, k, kT);
  k_f2b2<<<2 * (D_ * D_) / 2048, 256, 0, stream>>>(Wv, Wg, Wpair);
  k_proj2<1, 2><<<gpW, 512, 0, stream>>>(xn, Wpair, (bf16*)nullptr, vT);
  k_proj2<2, 1><<<gpW, 512, 0, stream>>>(xn, Wpair + W1, g, (bf16*)nullptr);

  // intra-chunk: masked scores (lower-tri tiles only) then s @ v
  // (chunk 0 gated inside ointra; no inter-chunk pass for t=0)
  k_scores<<<dim3(CH / 128, CH / 128, BATCH * TC), 256, 0, stream>>>(q, k, s);
  k_ointra<<<dim3(D_ / 128, CH / 128, BATCH * TC), 256, 0, stream>>>(s, vT, g, og);

  // k and s dead -> their regions hold the 6 kv slots. All outer products
  // in ONE launch (grid 1536), then in-place prefix sums, then all
  // inter-chunk GEMMs in ONE launch (grid 768).
  k_update_all<<<dim3(D_ / 128, D_ / 128, 6), 256, 0, stream>>>(vT, kT, kv01, kv2);
  k_add<<<(2 * D_ * D_) / 2048, 256, 0, stream>>>(kv01 + 2 * KV1, kv01);  // s1 += s0
  k_add<<<(2 * D_ * D_) / 2048, 256, 0, stream>>>(kv2, kv01 + 2 * KV1);   // s2 += s1
  k_ointer_all<<<dim3(D_ / 128, CH / 128, 6), 256, 0, stream>>>(q, kv01, kv2,
                                                                g, og);

  // kv slots dead; shared region hosts the bf16 Wp
  bf16* Wpb = (bf16*)shared;
  k_f2b<<<(D_ * D_) / 2048, 256, 0, stream>>>(Wp, Wpb);
  k_final2<<<gpW, 512, 0, stream>>>(og, Wpb, out);
}